// Round 1
// baseline (922.073 us; speedup 1.0000x reference)
//
#include <hip/hip_runtime.h>
#include <hip/hip_bf16.h>
#include <stdint.h>
#include <math.h>

typedef __bf16 bf16;
typedef __bf16 bf16x8 __attribute__((ext_vector_type(8)));
typedef float  f32x4  __attribute__((ext_vector_type(4)));

#define SD 2048      // sequence length
#define DM 2048      // model dim
#define NH 16        // heads
#define NKV 4        // kv heads
#define DHD 128      // head dim
#define NE 8         // experts
#define NNI 1024     // expert intermediate

// ---------------- workspace layout (bytes) ----------------
constexpr size_t OF_WQKVT = 0;                        // bf16 [3072][2048]
constexpr size_t OF_WGUT  = OF_WQKVT + 12582912ull;   // bf16 [8][2048][2048] (gate/up interleaved rows)
constexpr size_t OF_WDT   = OF_WGUT  + 67108864ull;   // bf16 [8][2048][1024]
constexpr size_t OF_WOT   = OF_WDT   + 33554432ull;   // bf16 [2048][2048]   (tb aliases later)
constexpr size_t OF_H     = OF_WOT   + 8388608ull;    // bf16 [2048][2048]   (ob aliases later)
constexpr size_t OF_QKV   = OF_H     + 8388608ull;    // f32  [2048][3072]
constexpr size_t OF_QB    = OF_QKV   + 25165824ull;   // bf16 [16][2048][128]
constexpr size_t OF_KB    = OF_QB    + 8388608ull;    // bf16 [4][2048][128] (combine aliases later)
constexpr size_t OF_VTB   = OF_KB    + 2097152ull;    // bf16 [4][128][2048]
constexpr size_t OF_X1    = OF_VTB   + 2097152ull;    // f32  [2048][2048]
constexpr size_t WS_NEED  = OF_X1    + 16777216ull;   // 184,549,376 B
// aliases (regions dead by the time these are written):
constexpr size_t OF_ACT  = OF_QKV;   // bf16 [8][2048][1024] = 33,554,432 B (== QKV+QB span)
constexpr size_t OF_TB   = OF_WOT;   // bf16 [2048][2048]
constexpr size_t OF_OB   = OF_H;     // bf16 [2048][2048]
constexpr size_t OF_COMB = OF_KB;    // f32  [2048][8]

// ---------------- async global->LDS (16B/lane, wave-uniform LDS base) ----------------
__device__ __forceinline__ void async16(void* lds, const void* g) {
  uint32_t lo = (uint32_t)(uintptr_t)lds;
  __builtin_amdgcn_global_load_lds(
      (const __attribute__((address_space(1))) uint32_t*)(uintptr_t)g,
      (__attribute__((address_space(3))) uint32_t*)lo,
      16, 0, 0);
}

// ---------------- generic f32 [R][C] -> bf16 [C*ost+oroff][R] transpose+convert ----------------
__global__ void transpose_cvt(const float* __restrict__ in, int ild, long long inb,
                              bf16* __restrict__ out, int old_, long long outb,
                              int ost, int oroff)
{
  __shared__ float tile[32][33];
  const float* ip = in + (long long)blockIdx.z * inb;
  bf16* op = out + (long long)blockIdx.z * outb;
  int r0 = blockIdx.y * 32, c0 = blockIdx.x * 32;
  int tx = threadIdx.x, ty = threadIdx.y; // 32 x 8
#pragma unroll
  for (int i = 0; i < 4; i++)
    tile[ty + i*8][tx] = ip[(size_t)(r0 + ty + i*8)*ild + c0 + tx];
  __syncthreads();
#pragma unroll
  for (int i = 0; i < 4; i++) {
    int cl = ty + i*8;
    op[(size_t)((c0 + cl)*ost + oroff)*old_ + r0 + tx] = (bf16)tile[tx][cl];
  }
}

// ---------------- rmsnorm f32 [S][2048] -> bf16 ----------------
__global__ __launch_bounds__(256)
void rmsnorm_k(const float* __restrict__ in, const float* __restrict__ w, bf16* __restrict__ outb)
{
  __shared__ float red[4];
  int s = blockIdx.x, t = threadIdx.x;
  const float* ip = in + (size_t)s * DM;
  float v[8]; float ss = 0.f;
#pragma unroll
  for (int i = 0; i < 8; i++) { v[i] = ip[t + i*256]; ss += v[i]*v[i]; }
#pragma unroll
  for (int off = 32; off > 0; off >>= 1) ss += __shfl_xor(ss, off);
  if ((t & 63) == 0) red[t >> 6] = ss;
  __syncthreads();
  float rn = rsqrtf((red[0]+red[1]+red[2]+red[3]) * (1.f/DM) + 1e-6f);
  bf16* op = outb + (size_t)s * DM;
#pragma unroll
  for (int i = 0; i < 8; i++) op[t + i*256] = (bf16)(v[i]*rn*w[t + i*256]);
}

// ---------------- q: rmsnorm(2048) + rope + 1/sqrt(DH), write [H][S][128] bf16 ----------------
__global__ __launch_bounds__(256)
void qrope_k(const float* __restrict__ qkv, const float* __restrict__ w, bf16* __restrict__ qout)
{
  __shared__ float row[2048];
  __shared__ float red[4];
  int s = blockIdx.x, t = threadIdx.x;
  const float* ip = qkv + (size_t)s * 3072;
  float ss = 0.f;
#pragma unroll
  for (int i = 0; i < 8; i++) { float x = ip[t + i*256]; row[t + i*256] = x; ss += x*x; }
#pragma unroll
  for (int off = 32; off > 0; off >>= 1) ss += __shfl_xor(ss, off);
  if ((t & 63) == 0) red[t >> 6] = ss;
  __syncthreads();
  float rn = rsqrtf((red[0]+red[1]+red[2]+red[3]) * (1.f/2048.f) + 1e-6f);
  const float sc = 0.08838834764831845f; // 1/sqrt(128)
#pragma unroll
  for (int i = 0; i < 8; i++) {
    int idx = t + i*256;
    int d = idx & 127;
    float val = row[idx]*rn*w[idx];
    float o;
    if (d < 64) {
      int fi = d & 31;
      float ang = (float)s * expf(-(float)fi * (13.815510557964274f/32.f)); // theta=1e6
      float c, sn; sincosf(ang, &sn, &c);
      float pv = row[idx ^ 32]*rn*w[idx ^ 32];
      o = (d < 32) ? (val*c - pv*sn) : (val*c + pv*sn);
    } else o = val;
    qout[((size_t)(idx >> 7)*SD + s)*DHD + d] = (bf16)(o * sc);
  }
}

// ---------------- k: rmsnorm(512) + rope, write [KV][S][128] bf16 ----------------
__global__ __launch_bounds__(128)
void krope_k(const float* __restrict__ qkv, const float* __restrict__ w, bf16* __restrict__ kout)
{
  __shared__ float row[512];
  __shared__ float red[2];
  int s = blockIdx.x, t = threadIdx.x;
  const float* ip = qkv + (size_t)s * 3072 + 2048;
  float ss = 0.f;
#pragma unroll
  for (int i = 0; i < 4; i++) { float x = ip[t + i*128]; row[t + i*128] = x; ss += x*x; }
#pragma unroll
  for (int off = 32; off > 0; off >>= 1) ss += __shfl_xor(ss, off);
  if ((t & 63) == 0) red[t >> 6] = ss;
  __syncthreads();
  float rn = rsqrtf((red[0]+red[1]) * (1.f/512.f) + 1e-6f);
#pragma unroll
  for (int i = 0; i < 4; i++) {
    int idx = t + i*128;
    int d = idx & 127;
    float val = row[idx]*rn*w[idx];
    float o;
    if (d < 64) {
      int fi = d & 31;
      float ang = (float)s * expf(-(float)fi * (13.815510557964274f/32.f));
      float c, sn; sincosf(ang, &sn, &c);
      float pv = row[idx ^ 32]*rn*w[idx ^ 32];
      o = (d < 32) ? (val*c - pv*sn) : (val*c + pv*sn);
    } else o = val;
    kout[((size_t)(idx >> 7)*SD + s)*DHD + d] = (bf16)o;
  }
}

// ---------------- GEMM: C[M][N] = A(bf16 [M][K]) @ BT(bf16 [N][K])^T, epilogue variants ----------------
// EPI 0: C f32 plain    1: C = acc + res    2: gate/up->silu->act bf16    3: down: out (+)= comb*acc (+x1 if first)
template<int EPI>
__global__ __launch_bounds__(256)
void gemm_bt(const bf16* __restrict__ Ag, const bf16* __restrict__ Bg,
             float* __restrict__ Cg, bf16* __restrict__ actg,
             const float* __restrict__ res, const float* __restrict__ comb,
             int M, int N, int K, int expert, int first,
             long long batchB, long long batchOut)
{
  __shared__ __align__(16) bf16 As[2][128*32];
  __shared__ __align__(16) bf16 Bs[2][128*32];
  const int tid = threadIdx.x;
  const int wv = tid >> 6, l = tid & 63;
  const int wm = wv >> 1, wn = wv & 1;
  const int bm = blockIdx.y * 128, bn = blockIdx.x * 128;
  const bf16* A  = Ag;
  const bf16* BT = Bg + (long long)blockIdx.z * batchB;

  f32x4 acc[4][4];
  const f32x4 vz = {0.f, 0.f, 0.f, 0.f};
#pragma unroll
  for (int i = 0; i < 4; i++)
#pragma unroll
    for (int j = 0; j < 4; j++) acc[i][j] = vz;

  auto stage = [&](int kt, int b) {
    int k0 = kt * 32;
#pragma unroll
    for (int c = 0; c < 2; c++) {
      int chunk = wv*2 + c;
      int row = chunk*16 + (l >> 2);
      int kc = (l & 3) * 8;
      async16(&As[b][chunk*512], A  + (size_t)(bm + row)*K + k0 + kc);
      async16(&Bs[b][chunk*512], BT + (size_t)(bn + row)*K + k0 + kc);
    }
  };

  int nkt = K >> 5;
  stage(0, 0);
  int buf = 0;
  for (int kt = 0; kt < nkt; ++kt) {
    __syncthreads();                    // drains vmcnt -> staged tile visible
    if (kt + 1 < nkt) stage(kt + 1, buf ^ 1);
    bf16x8 af[4], bfv[4];
#pragma unroll
    for (int m = 0; m < 4; m++)
      af[m] = *(const bf16x8*)&As[buf][(wm*64 + m*16 + (l & 15))*32 + (l >> 4)*8];
#pragma unroll
    for (int n = 0; n < 4; n++)
      bfv[n] = *(const bf16x8*)&Bs[buf][(wn*64 + n*16 + (l & 15))*32 + (l >> 4)*8];
#pragma unroll
    for (int m = 0; m < 4; m++)
#pragma unroll
      for (int n = 0; n < 4; n++)
        acc[m][n] = __builtin_amdgcn_mfma_f32_16x16x32_bf16(af[m], bfv[n], acc[m][n], 0, 0, 0);
    buf ^= 1;
  }

#pragma unroll
  for (int m = 0; m < 4; m++) {
#pragma unroll
    for (int n = 0; n < 4; n++) {
#pragma unroll
      for (int r = 0; r < 4; r++) {
        int row = bm + wm*64 + m*16 + (l >> 4)*4 + r;
        int col = bn + wn*64 + n*16 + (l & 15);
        float v = acc[m][n][r];
        if (EPI == 0) {
          Cg[(size_t)row*N + col] = v;
        } else if (EPI == 1) {
          Cg[(size_t)row*N + col] = v + res[(size_t)row*N + col];
        } else if (EPI == 2) {
          float p = __shfl_xor(v, 1);       // partner column (gate<->up pair)
          if (!(l & 1)) {
            float a = v / (1.f + __expf(-v)) * p;  // silu(gate)*up
            bf16* ap = actg + (long long)blockIdx.z * batchOut;
            ap[(size_t)row*(N >> 1) + (col >> 1)] = (bf16)a;
          }
        } else { // EPI == 3
          float scv = comb[row*8 + expert];
          size_t o = (size_t)row*N + col;
          if (first) Cg[o] = res[o] + scv * v;
          else       Cg[o] += scv * v;
        }
      }
    }
  }
}

// ---------------- flash attention: causal GQA, 64-row q tiles, 4 waves ----------------
__global__ __launch_bounds__(256)
void flash(const bf16* __restrict__ qb, const bf16* __restrict__ kb,
           const bf16* __restrict__ vtb, bf16* __restrict__ ob)
{
  __shared__ __align__(16) bf16 Ks[64*128];   // [kv][d], XOR-swizzled 16B blocks
  __shared__ __align__(16) bf16 Vs[128*64];   // [d][kv], XOR-swizzled
  __shared__ __align__(16) bf16 Ps[4*16*64];  // per-wave P tiles, XOR-swizzled
  const int tid = threadIdx.x, wv = tid >> 6, l = tid & 63;
  const int qt = blockIdx.x, h = blockIdx.y, g = h >> 2;

  const int qrow = qt*64 + wv*16 + (l & 15);
  bf16x8 qf[4];
#pragma unroll
  for (int f = 0; f < 4; f++)
    qf[f] = *(const bf16x8*)(qb + ((size_t)h*SD + qrow)*DHD + f*32 + (l >> 4)*8);

  float mrun[4], lrun[4];
#pragma unroll
  for (int r = 0; r < 4; r++) { mrun[r] = -1e30f; lrun[r] = 0.f; }
  f32x4 oac[8];
  const f32x4 vz = {0.f, 0.f, 0.f, 0.f};
#pragma unroll
  for (int d = 0; d < 8; d++) oac[d] = vz;

  for (int j = 0; j <= qt; ++j) {
#pragma unroll
    for (int c = 0; c < 4; c++) {
      int chunk = wv*4 + c;
      int rk = chunk*4 + (l >> 4);
      int ck = (l & 15) ^ (rk & 7);                       // pre-swizzled global source
      async16(&Ks[chunk*512], kb + ((size_t)g*SD + j*64 + rk)*DHD + ck*8);
      int rv = chunk*8 + (l >> 3);
      int cv = (l & 7) ^ (rv & 7);
      async16(&Vs[chunk*512], vtb + ((size_t)g*DHD + rv)*SD + j*64 + cv*8);
    }
    __syncthreads();

    f32x4 sf[4];
#pragma unroll
    for (int n = 0; n < 4; n++) sf[n] = vz;
#pragma unroll
    for (int f = 0; f < 4; f++) {
#pragma unroll
      for (int n = 0; n < 4; n++) {
        int row = n*16 + (l & 15);
        int cb = (f*64 + (l >> 4)*16) ^ ((row & 7) << 4);
        bf16x8 kf = *(const bf16x8*)((const char*)Ks + row*256 + cb);
        sf[n] = __builtin_amdgcn_mfma_f32_16x16x32_bf16(qf[f], kf, sf[n], 0, 0, 0);
      }
    }
    if (j == qt) {
#pragma unroll
      for (int n = 0; n < 4; n++)
#pragma unroll
        for (int r = 0; r < 4; r++) {
          int kvp = n*16 + (l & 15);
          int qp  = wv*16 + (l >> 4)*4 + r;
          if (kvp > qp) sf[n][r] = -1e30f;
        }
    }
    // online softmax (row spread over 16-lane group; each lane owns 4 q-rows r)
#pragma unroll
    for (int r = 0; r < 4; r++) {
      float tm = fmaxf(fmaxf(sf[0][r], sf[1][r]), fmaxf(sf[2][r], sf[3][r]));
#pragma unroll
      for (int off = 8; off > 0; off >>= 1) tm = fmaxf(tm, __shfl_xor(tm, off));
      float mn = fmaxf(mrun[r], tm);
      float fac = __expf(mrun[r] - mn);
      mrun[r] = mn;
      float pe[4]; float ps = 0.f;
#pragma unroll
      for (int n = 0; n < 4; n++) { pe[n] = __expf(sf[n][r] - mn); ps += pe[n]; }
#pragma unroll
      for (int off = 8; off > 0; off >>= 1) ps += __shfl_xor(ps, off);
      lrun[r] = lrun[r]*fac + ps;
#pragma unroll
      for (int d = 0; d < 8; d++) oac[d][r] *= fac;
      int prow = (l >> 4)*4 + r;
#pragma unroll
      for (int n = 0; n < 4; n++) {
        int cbp = ((n*16 + (l & 15))*2) ^ ((prow & 7) << 4);
        *(bf16*)((char*)Ps + wv*2048 + prow*128 + cbp) = (bf16)pe[n];
      }
    }
    // PV
#pragma unroll
    for (int ks = 0; ks < 2; ks++) {
      int pr = l & 15;
      int cbp = (ks*64 + (l >> 4)*16) ^ ((pr & 7) << 4);
      bf16x8 pa = *(const bf16x8*)((const char*)Ps + wv*2048 + pr*128 + cbp);
#pragma unroll
      for (int dt = 0; dt < 8; dt++) {
        int rv = dt*16 + (l & 15);
        int cbv = (ks*64 + (l >> 4)*16) ^ ((rv & 7) << 4);
        bf16x8 vf = *(const bf16x8*)((const char*)Vs + rv*128 + cbv);
        oac[dt] = __builtin_amdgcn_mfma_f32_16x16x32_bf16(pa, vf, oac[dt], 0, 0, 0);
      }
    }
    __syncthreads();
  }
#pragma unroll
  for (int dt = 0; dt < 8; dt++)
#pragma unroll
    for (int r = 0; r < 4; r++) {
      int s = qt*64 + wv*16 + (l >> 4)*4 + r;
      int d = dt*16 + (l & 15);
      ob[(size_t)s*DM + h*DHD + d] = (bf16)(oac[dt][r] / lrun[r]);
    }
}

// ---------------- router: f32 path from x1 (own rmsnorm), sigmoid top-2 ----------------
__global__ __launch_bounds__(256)
void router_k(const float* __restrict__ x1, const float* __restrict__ w2,
              const float* __restrict__ rw, const float* __restrict__ rb,
              float* __restrict__ comb)
{
  int tok = blockIdx.x*4 + (threadIdx.x >> 6);
  int l = threadIdx.x & 63;
  const float* ip = x1 + (size_t)tok * DM;
  float tv[32]; float ss = 0.f;
#pragma unroll
  for (int i = 0; i < 32; i++) { float v = ip[l + i*64]; tv[i] = v; ss += v*v; }
#pragma unroll
  for (int off = 32; off > 0; off >>= 1) ss += __shfl_xor(ss, off);
  float rn = rsqrtf(ss * (1.f/DM) + 1e-6f);
  float acc[8];
#pragma unroll
  for (int e = 0; e < 8; e++) acc[e] = 0.f;
#pragma unroll
  for (int i = 0; i < 32; i++) {
    int d = l + i*64;
    float tval = tv[i]*rn*w2[d];
#pragma unroll
    for (int e = 0; e < 8; e++) acc[e] += tval * rw[d*8 + e];
  }
#pragma unroll
  for (int e = 0; e < 8; e++)
#pragma unroll
    for (int off = 32; off > 0; off >>= 1) acc[e] += __shfl_xor(acc[e], off);
  if (l == 0) {
    float sig[8], scv[8];
#pragma unroll
    for (int e = 0; e < 8; e++) { sig[e] = 1.f/(1.f + expf(-acc[e])); scv[e] = sig[e] + rb[e]; }
    int i0 = 0;
#pragma unroll
    for (int e = 1; e < 8; e++) if (scv[e] > scv[i0]) i0 = e;
    int i1 = (i0 == 0) ? 1 : 0;
#pragma unroll
    for (int e = 0; e < 8; e++) if (e != i0 && scv[e] > scv[i1]) i1 = e;
    float a0 = sig[i0], a1 = sig[i1], inv = 1.f/(a0 + a1);
#pragma unroll
    for (int e = 0; e < 8; e++) comb[tok*8 + e] = 0.f;
    comb[tok*8 + i0] = a0*inv;
    comb[tok*8 + i1] = a1*inv;
  }
}

// ---------------- launch ----------------
extern "C" void kernel_launch(void* const* d_in, const int* in_sizes, int n_in,
                              void* d_out, int out_size, void* d_ws, size_t ws_size,
                              hipStream_t stream) {
  if (ws_size < WS_NEED) return;  // fail loudly (out stays poisoned)
  const float* x     = (const float*)d_in[0];
  const float* ln1_w = (const float*)d_in[1];
  const float* ln2_w = (const float*)d_in[2];
  const float* wq    = (const float*)d_in[3];
  const float* wk    = (const float*)d_in[4];
  const float* wv    = (const float*)d_in[5];
  const float* wo    = (const float*)d_in[6];
  const float* qnw   = (const float*)d_in[7];
  const float* knw   = (const float*)d_in[8];
  const float* rw    = (const float*)d_in[9];
  const float* rb    = (const float*)d_in[10];
  const float* wg    = (const float*)d_in[11];
  const float* wu    = (const float*)d_in[12];
  const float* wd    = (const float*)d_in[13];

  char* ws = (char*)d_ws;
  bf16*  wqkvT = (bf16*)(ws + OF_WQKVT);
  bf16*  wguT  = (bf16*)(ws + OF_WGUT);
  bf16*  wdT   = (bf16*)(ws + OF_WDT);
  bf16*  woT   = (bf16*)(ws + OF_WOT);
  bf16*  hb    = (bf16*)(ws + OF_H);
  float* qkvf  = (float*)(ws + OF_QKV);
  bf16*  qbb   = (bf16*)(ws + OF_QB);
  bf16*  kbb   = (bf16*)(ws + OF_KB);
  bf16*  vtbb  = (bf16*)(ws + OF_VTB);
  float* x1f   = (float*)(ws + OF_X1);
  bf16*  actb  = (bf16*)(ws + OF_ACT);
  bf16*  tbb   = (bf16*)(ws + OF_TB);
  bf16*  obb   = (bf16*)(ws + OF_OB);
  float* combf = (float*)(ws + OF_COMB);
  float* outp  = (float*)d_out;

  dim3 b32(32, 8);
  // weight transposes (f32 [K][N] -> bf16 [N][K])
  transpose_cvt<<<dim3(64,64,1), b32, 0, stream>>>(wq, 2048, 0, wqkvT, 2048, 0, 1, 0);
  transpose_cvt<<<dim3(16,64,1), b32, 0, stream>>>(wk,  512, 0, wqkvT, 2048, 0, 1, 2048);
  transpose_cvt<<<dim3(16,64,1), b32, 0, stream>>>(wv,  512, 0, wqkvT, 2048, 0, 1, 2560);
  transpose_cvt<<<dim3(64,64,1), b32, 0, stream>>>(wo, 2048, 0, woT,   2048, 0, 1, 0);
  transpose_cvt<<<dim3(32,64,8), b32, 0, stream>>>(wg, 1024, 2048ll*1024, wguT, 2048, 2048ll*2048, 2, 0);
  transpose_cvt<<<dim3(32,64,8), b32, 0, stream>>>(wu, 1024, 2048ll*1024, wguT, 2048, 2048ll*2048, 2, 1);
  transpose_cvt<<<dim3(64,32,8), b32, 0, stream>>>(wd, 2048, 1024ll*2048, wdT,  1024, 2048ll*1024, 1, 0);

  rmsnorm_k<<<2048, 256, 0, stream>>>(x, ln1_w, hb);
  gemm_bt<0><<<dim3(24,16,1), 256, 0, stream>>>(hb, wqkvT, qkvf, nullptr, nullptr, nullptr,
                                                2048, 3072, 2048, 0, 0, 0, 0);
  qrope_k<<<2048, 256, 0, stream>>>(qkvf, qnw, qbb);
  krope_k<<<2048, 128, 0, stream>>>(qkvf, knw, kbb);
  transpose_cvt<<<dim3(16,64,1), b32, 0, stream>>>(qkvf + 2560, 3072, 0, vtbb, 2048, 0, 1, 0);

  flash<<<dim3(32,16,1), 256, 0, stream>>>(qbb, kbb, vtbb, obb);

  gemm_bt<1><<<dim3(16,16,1), 256, 0, stream>>>(obb, woT, x1f, nullptr, x, nullptr,
                                                2048, 2048, 2048, 0, 0, 0, 0);
  rmsnorm_k<<<2048, 256, 0, stream>>>(x1f, ln2_w, tbb);
  router_k<<<512, 256, 0, stream>>>(x1f, ln2_w, rw, rb, combf);

  // MoE (dense over all 8 experts; combine zeros out the non-selected)
  gemm_bt<2><<<dim3(16,16,8), 256, 0, stream>>>(tbb, wguT, nullptr, actb, nullptr, nullptr,
                                                2048, 2048, 2048, 0, 0, 2048ll*2048, 2048ll*1024);
  for (int e = 0; e < 8; e++)
    gemm_bt<3><<<dim3(16,16,1), 256, 0, stream>>>(actb + (size_t)e*2048*1024, wdT + (size_t)e*2048*1024,
                                                  outp, nullptr, x1f, combf,
                                                  2048, 2048, 1024, e, (e == 0) ? 1 : 0, 0, 0);
}

// Round 2
// 630.352 us; speedup vs baseline: 1.4628x; 1.4628x over previous
//
#include <hip/hip_runtime.h>
#include <hip/hip_bf16.h>
#include <stdint.h>
#include <math.h>

typedef __bf16 bf16;
typedef __bf16 bf16x8 __attribute__((ext_vector_type(8)));
typedef __bf16 bf16x4 __attribute__((ext_vector_type(4)));
typedef float  f32x4  __attribute__((ext_vector_type(4)));

#define SD 2048      // sequence length
#define DM 2048      // model dim
#define NH 16        // heads
#define NKV 4        // kv heads
#define DHD 128      // head dim
#define NE 8         // experts
#define NNI 1024     // expert intermediate

// ---------------- workspace layout (bytes) ----------------
constexpr size_t OF_WQKVT = 0;                        // bf16 [3072][2048]
constexpr size_t OF_WGUT  = OF_WQKVT + 12582912ull;   // bf16 [8][2048][2048] (gate/up interleaved rows)
constexpr size_t OF_WDT   = OF_WGUT  + 67108864ull;   // bf16 [8][2048][1024]
constexpr size_t OF_WOT   = OF_WDT   + 33554432ull;   // bf16 [2048][2048]   (tb, tmp1 alias later)
constexpr size_t OF_H     = OF_WOT   + 8388608ull;    // bf16 [2048][2048]   (ob, tmp0 alias later)
constexpr size_t OF_QKV   = OF_H     + 8388608ull;    // f32  [2048][3072]
constexpr size_t OF_QB    = OF_QKV   + 25165824ull;   // bf16 [16][2048][128]
constexpr size_t OF_KB    = OF_QB    + 8388608ull;    // bf16 [4][2048][128] (router scratch aliases later)
constexpr size_t OF_VTB   = OF_KB    + 2097152ull;    // bf16 [4][128][2048]
constexpr size_t OF_X1    = OF_VTB   + 2097152ull;    // f32  [2048][2048]
constexpr size_t WS_NEED  = OF_X1    + 16777216ull;   // 184,549,376 B
// aliases (regions dead by the time these are written):
constexpr size_t OF_ACT  = OF_QKV;          // bf16 [8][2048][1024] (== QKV+QB span, dead after flash)
constexpr size_t OF_TB   = OF_WOT;          // bf16 [2048][2048] (woT dead after o-proj)
constexpr size_t OF_OB   = OF_H;            // bf16 [2048][2048] (h dead after qkv gemm)
// router/scheduler scratch inside OF_KB (k-cache dead after flash):
constexpr size_t OF_CNT  = OF_KB;           // int [8]
constexpr size_t OF_BLKE = OF_KB + 256;     // int [40]
constexpr size_t OF_BLKR = OF_KB + 512;     // int [40]
constexpr size_t OF_TOT  = OF_KB + 768;     // int [1]
constexpr size_t OF_TOPI = OF_KB + 1024;    // int [2048]
constexpr size_t OF_TOPW = OF_KB + 16384;   // float [2048][2]
constexpr size_t OF_IDXL = OF_KB + 65536;   // int [8][2048]
constexpr size_t OF_WLST = OF_KB + 131072;  // float [8][2048]
constexpr size_t OF_TMP0 = OF_H;            // bf16 [2048][2048] (ob dead after o-proj)
constexpr size_t OF_TMP1 = OF_WOT;          // bf16 [2048][2048] (tb dead after gate/up)

// ---------------- async global->LDS (16B/lane, wave-uniform LDS base) ----------------
__device__ __forceinline__ void async16(void* lds, const void* g) {
  uint32_t lo = (uint32_t)(uintptr_t)lds;
  __builtin_amdgcn_global_load_lds(
      (const __attribute__((address_space(1))) uint32_t*)(uintptr_t)g,
      (__attribute__((address_space(3))) uint32_t*)lo,
      16, 0, 0);
}

// ---------------- generic f32 [R][C] -> bf16 [C*ost+oroff][R] transpose+convert ----------------
__global__ void transpose_cvt(const float* __restrict__ in, int ild, long long inb,
                              bf16* __restrict__ out, int old_, long long outb,
                              int ost, int oroff)
{
  __shared__ float tile[32][33];
  const float* ip = in + (long long)blockIdx.z * inb;
  bf16* op = out + (long long)blockIdx.z * outb;
  int r0 = blockIdx.y * 32, c0 = blockIdx.x * 32;
  int tx = threadIdx.x, ty = threadIdx.y; // 32 x 8
#pragma unroll
  for (int i = 0; i < 4; i++)
    tile[ty + i*8][tx] = ip[(size_t)(r0 + ty + i*8)*ild + c0 + tx];
  __syncthreads();
#pragma unroll
  for (int i = 0; i < 4; i++) {
    int cl = ty + i*8;
    op[(size_t)((c0 + cl)*ost + oroff)*old_ + r0 + tx] = (bf16)tile[tx][cl];
  }
}

// ---------------- rmsnorm f32 [S][2048] -> bf16 ----------------
__global__ __launch_bounds__(256)
void rmsnorm_k(const float* __restrict__ in, const float* __restrict__ w, bf16* __restrict__ outb)
{
  __shared__ float red[4];
  int s = blockIdx.x, t = threadIdx.x;
  const float* ip = in + (size_t)s * DM;
  float v[8]; float ss = 0.f;
#pragma unroll
  for (int i = 0; i < 8; i++) { v[i] = ip[t + i*256]; ss += v[i]*v[i]; }
#pragma unroll
  for (int off = 32; off > 0; off >>= 1) ss += __shfl_xor(ss, off);
  if ((t & 63) == 0) red[t >> 6] = ss;
  __syncthreads();
  float rn = rsqrtf((red[0]+red[1]+red[2]+red[3]) * (1.f/DM) + 1e-6f);
  bf16* op = outb + (size_t)s * DM;
#pragma unroll
  for (int i = 0; i < 8; i++) op[t + i*256] = (bf16)(v[i]*rn*w[t + i*256]);
}

// ---------------- q: rmsnorm(2048) + rope + 1/sqrt(DH), write [H][S][128] bf16 ----------------
__global__ __launch_bounds__(256)
void qrope_k(const float* __restrict__ qkv, const float* __restrict__ w, bf16* __restrict__ qout)
{
  __shared__ float row[2048];
  __shared__ float red[4];
  int s = blockIdx.x, t = threadIdx.x;
  const float* ip = qkv + (size_t)s * 3072;
  float ss = 0.f;
#pragma unroll
  for (int i = 0; i < 8; i++) { float x = ip[t + i*256]; row[t + i*256] = x; ss += x*x; }
#pragma unroll
  for (int off = 32; off > 0; off >>= 1) ss += __shfl_xor(ss, off);
  if ((t & 63) == 0) red[t >> 6] = ss;
  __syncthreads();
  float rn = rsqrtf((red[0]+red[1]+red[2]+red[3]) * (1.f/2048.f) + 1e-6f);
  const float sc = 0.08838834764831845f; // 1/sqrt(128)
#pragma unroll
  for (int i = 0; i < 8; i++) {
    int idx = t + i*256;
    int d = idx & 127;
    float val = row[idx]*rn*w[idx];
    float o;
    if (d < 64) {
      int fi = d & 31;
      float ang = (float)s * expf(-(float)fi * (13.815510557964274f/32.f)); // theta=1e6
      float c, sn; sincosf(ang, &sn, &c);
      float pv = row[idx ^ 32]*rn*w[idx ^ 32];
      o = (d < 32) ? (val*c - pv*sn) : (val*c + pv*sn);
    } else o = val;
    qout[((size_t)(idx >> 7)*SD + s)*DHD + d] = (bf16)(o * sc);
  }
}

// ---------------- k: rmsnorm(512) + rope, write [KV][S][128] bf16 ----------------
__global__ __launch_bounds__(128)
void krope_k(const float* __restrict__ qkv, const float* __restrict__ w, bf16* __restrict__ kout)
{
  __shared__ float row[512];
  __shared__ float red[2];
  int s = blockIdx.x, t = threadIdx.x;
  const float* ip = qkv + (size_t)s * 3072 + 2048;
  float ss = 0.f;
#pragma unroll
  for (int i = 0; i < 4; i++) { float x = ip[t + i*128]; row[t + i*128] = x; ss += x*x; }
#pragma unroll
  for (int off = 32; off > 0; off >>= 1) ss += __shfl_xor(ss, off);
  if ((t & 63) == 0) red[t >> 6] = ss;
  __syncthreads();
  float rn = rsqrtf((red[0]+red[1]) * (1.f/512.f) + 1e-6f);
#pragma unroll
  for (int i = 0; i < 4; i++) {
    int idx = t + i*128;
    int d = idx & 127;
    float val = row[idx]*rn*w[idx];
    float o;
    if (d < 64) {
      int fi = d & 31;
      float ang = (float)s * expf(-(float)fi * (13.815510557964274f/32.f));
      float c, sn; sincosf(ang, &sn, &c);
      float pv = row[idx ^ 32]*rn*w[idx ^ 32];
      o = (d < 32) ? (val*c - pv*sn) : (val*c + pv*sn);
    } else o = val;
    kout[((size_t)(idx >> 7)*SD + s)*DHD + d] = (bf16)o;
  }
}

// ---------------- GEMM: C[M][N] = A(bf16 [M][K]) @ BT(bf16 [N][K])^T ----------------
// EPI 0: C f32 plain    1: C = acc + res
template<int EPI>
__global__ __launch_bounds__(256)
void gemm_bt(const bf16* __restrict__ Ag, const bf16* __restrict__ Bg,
             float* __restrict__ Cg, const float* __restrict__ res,
             int M, int N, int K)
{
  __shared__ __align__(16) bf16 As[2][128*32];
  __shared__ __align__(16) bf16 Bs[2][128*32];
  const int tid = threadIdx.x;
  const int wv = tid >> 6, l = tid & 63;
  const int wm = wv >> 1, wn = wv & 1;
  const int bm = blockIdx.y * 128, bn = blockIdx.x * 128;
  const bf16* A  = Ag;
  const bf16* BT = Bg;

  f32x4 acc[4][4];
  const f32x4 vz = {0.f, 0.f, 0.f, 0.f};
#pragma unroll
  for (int i = 0; i < 4; i++)
#pragma unroll
    for (int j = 0; j < 4; j++) acc[i][j] = vz;

  auto stage = [&](int kt, int b) {
    int k0 = kt * 32;
#pragma unroll
    for (int c = 0; c < 2; c++) {
      int chunk = wv*2 + c;
      int row = chunk*16 + (l >> 2);
      int kc = (l & 3) * 8;
      async16(&As[b][chunk*512], A  + (size_t)(bm + row)*K + k0 + kc);
      async16(&Bs[b][chunk*512], BT + (size_t)(bn + row)*K + k0 + kc);
    }
  };

  int nkt = K >> 5;
  stage(0, 0);
  int buf = 0;
  for (int kt = 0; kt < nkt; ++kt) {
    __syncthreads();                    // drains vmcnt -> staged tile visible
    if (kt + 1 < nkt) stage(kt + 1, buf ^ 1);
    bf16x8 af[4], bfv[4];
#pragma unroll
    for (int m = 0; m < 4; m++)
      af[m] = *(const bf16x8*)&As[buf][(wm*64 + m*16 + (l & 15))*32 + (l >> 4)*8];
#pragma unroll
    for (int n = 0; n < 4; n++)
      bfv[n] = *(const bf16x8*)&Bs[buf][(wn*64 + n*16 + (l & 15))*32 + (l >> 4)*8];
#pragma unroll
    for (int m = 0; m < 4; m++)
#pragma unroll
      for (int n = 0; n < 4; n++)
        acc[m][n] = __builtin_amdgcn_mfma_f32_16x16x32_bf16(af[m], bfv[n], acc[m][n], 0, 0, 0);
    buf ^= 1;
  }

#pragma unroll
  for (int m = 0; m < 4; m++) {
#pragma unroll
    for (int n = 0; n < 4; n++) {
#pragma unroll
      for (int r = 0; r < 4; r++) {
        int row = bm + wm*64 + m*16 + (l >> 4)*4 + r;
        int col = bn + wn*64 + n*16 + (l & 15);
        float v = acc[m][n][r];
        if (EPI == 0) {
          Cg[(size_t)row*N + col] = v;
        } else {
          Cg[(size_t)row*N + col] = v + res[(size_t)row*N + col];
        }
      }
    }
  }
}

// ---------------- MoE gate/up GEMM: gathered A rows, silu(gate)*up epilogue ----------------
__global__ __launch_bounds__(256)
void gemm_moe_gu(const bf16* __restrict__ tb, const bf16* __restrict__ wgu,
                 bf16* __restrict__ act,
                 const int* __restrict__ cnt, const int* __restrict__ blk_e,
                 const int* __restrict__ blk_r0, const int* __restrict__ total_nblk,
                 const int* __restrict__ idxlist)
{
  const int by = blockIdx.y;
  if (by >= *total_nblk) return;
  const int e = blk_e[by], r0 = blk_r0[by], cn = cnt[e];
  __shared__ __align__(16) bf16 As[2][128*32];
  __shared__ __align__(16) bf16 Bs[2][128*32];
  const int tid = threadIdx.x;
  const int wv = tid >> 6, l = tid & 63;
  const int wm = wv >> 1, wn = wv & 1;
  const int bn = blockIdx.x * 128;
  const bf16* BT = wgu + (size_t)e*2048*2048;

  // gathered A row pointers (K-loop invariant)
  const bf16* Arow[2];
#pragma unroll
  for (int c = 0; c < 2; c++) {
    int chunk = wv*2 + c;
    int rp = r0 + chunk*16 + (l >> 2);
    int tok = (rp < cn) ? (idxlist[e*2048 + rp] & 0xFFFF) : 0;
    Arow[c] = tb + (size_t)tok*2048 + (l & 3)*8;
  }

  f32x4 acc[4][4];
  const f32x4 vz = {0.f, 0.f, 0.f, 0.f};
#pragma unroll
  for (int i = 0; i < 4; i++)
#pragma unroll
    for (int j = 0; j < 4; j++) acc[i][j] = vz;

  auto stage = [&](int kt, int b) {
    int k0 = kt * 32;
#pragma unroll
    for (int c = 0; c < 2; c++) {
      int chunk = wv*2 + c;
      int row = chunk*16 + (l >> 2);
      int kc = (l & 3) * 8;
      async16(&As[b][chunk*512], Arow[c] + k0);
      async16(&Bs[b][chunk*512], BT + (size_t)(bn + row)*2048 + k0 + kc);
    }
  };

  stage(0, 0);
  int buf = 0;
  for (int kt = 0; kt < 64; ++kt) {
    __syncthreads();
    if (kt + 1 < 64) stage(kt + 1, buf ^ 1);
    bf16x8 af[4], bfv[4];
#pragma unroll
    for (int m = 0; m < 4; m++)
      af[m] = *(const bf16x8*)&As[buf][(wm*64 + m*16 + (l & 15))*32 + (l >> 4)*8];
#pragma unroll
    for (int n = 0; n < 4; n++)
      bfv[n] = *(const bf16x8*)&Bs[buf][(wn*64 + n*16 + (l & 15))*32 + (l >> 4)*8];
#pragma unroll
    for (int m = 0; m < 4; m++)
#pragma unroll
      for (int n = 0; n < 4; n++)
        acc[m][n] = __builtin_amdgcn_mfma_f32_16x16x32_bf16(af[m], bfv[n], acc[m][n], 0, 0, 0);
    buf ^= 1;
  }

  bf16* ap = act + (size_t)e*2048*1024;
#pragma unroll
  for (int m = 0; m < 4; m++) {
#pragma unroll
    for (int n = 0; n < 4; n++) {
#pragma unroll
      for (int r = 0; r < 4; r++) {
        int lrow = wm*64 + m*16 + (l >> 4)*4 + r;
        int col = bn + wn*64 + n*16 + (l & 15);
        float v = acc[m][n][r];
        float p = __shfl_xor(v, 1);        // partner column (gate<->up pair)
        if (!(l & 1)) {
          float a = v / (1.f + __expf(-v)) * p;   // silu(gate)*up
          ap[(size_t)(r0 + lrow)*1024 + (col >> 1)] = (bf16)a;
        }
      }
    }
  }
}

// ---------------- MoE down GEMM: scatter w*acc to rank-indexed tmp buffers ----------------
__global__ __launch_bounds__(256)
void gemm_moe_dn(const bf16* __restrict__ act, const bf16* __restrict__ wdt,
                 bf16* __restrict__ tmp0, bf16* __restrict__ tmp1,
                 const int* __restrict__ cnt, const int* __restrict__ blk_e,
                 const int* __restrict__ blk_r0, const int* __restrict__ total_nblk,
                 const int* __restrict__ idxlist, const float* __restrict__ wlist)
{
  const int by = blockIdx.y;
  if (by >= *total_nblk) return;
  const int e = blk_e[by], r0 = blk_r0[by], cn = cnt[e];
  __shared__ __align__(16) bf16 As[2][128*32];
  __shared__ __align__(16) bf16 Bs[2][128*32];
  const int tid = threadIdx.x;
  const int wv = tid >> 6, l = tid & 63;
  const int wm = wv >> 1, wn = wv & 1;
  const int bn = blockIdx.x * 128;
  const bf16* A  = act + (size_t)e*2048*1024 + (size_t)r0*1024;
  const bf16* BT = wdt + (size_t)e*2048*1024;

  f32x4 acc[4][4];
  const f32x4 vz = {0.f, 0.f, 0.f, 0.f};
#pragma unroll
  for (int i = 0; i < 4; i++)
#pragma unroll
    for (int j = 0; j < 4; j++) acc[i][j] = vz;

  auto stage = [&](int kt, int b) {
    int k0 = kt * 32;
#pragma unroll
    for (int c = 0; c < 2; c++) {
      int chunk = wv*2 + c;
      int row = chunk*16 + (l >> 2);
      int kc = (l & 3) * 8;
      async16(&As[b][chunk*512], A  + (size_t)row*1024 + k0 + kc);
      async16(&Bs[b][chunk*512], BT + (size_t)(bn + row)*1024 + k0 + kc);
    }
  };

  stage(0, 0);
  int buf = 0;
  for (int kt = 0; kt < 32; ++kt) {
    __syncthreads();
    if (kt + 1 < 32) stage(kt + 1, buf ^ 1);
    bf16x8 af[4], bfv[4];
#pragma unroll
    for (int m = 0; m < 4; m++)
      af[m] = *(const bf16x8*)&As[buf][(wm*64 + m*16 + (l & 15))*32 + (l >> 4)*8];
#pragma unroll
    for (int n = 0; n < 4; n++)
      bfv[n] = *(const bf16x8*)&Bs[buf][(wn*64 + n*16 + (l & 15))*32 + (l >> 4)*8];
#pragma unroll
    for (int m = 0; m < 4; m++)
#pragma unroll
      for (int n = 0; n < 4; n++)
        acc[m][n] = __builtin_amdgcn_mfma_f32_16x16x32_bf16(af[m], bfv[n], acc[m][n], 0, 0, 0);
    buf ^= 1;
  }

#pragma unroll
  for (int m = 0; m < 4; m++) {
#pragma unroll
    for (int n = 0; n < 4; n++) {
#pragma unroll
      for (int r = 0; r < 4; r++) {
        int lrow = wm*64 + m*16 + (l >> 4)*4 + r;
        int rie = r0 + lrow;
        if (rie < cn) {
          int col = bn + wn*64 + n*16 + (l & 15);
          int pk = idxlist[e*2048 + rie];
          int t = pk & 0xFFFF, rank = pk >> 16;
          float w = wlist[e*2048 + rie];
          bf16* dst = rank ? tmp1 : tmp0;
          dst[(size_t)t*2048 + col] = (bf16)(w * acc[m][n][r]);
        }
      }
    }
  }
}

// ---------------- router: f32 path from x1 (own rmsnorm), sigmoid top-2 per token ----------------
__global__ __launch_bounds__(256)
void router_k(const float* __restrict__ x1, const float* __restrict__ w2,
              const float* __restrict__ rw, const float* __restrict__ rb,
              int* __restrict__ top_i, float* __restrict__ top_w)
{
  int tok = blockIdx.x*4 + (threadIdx.x >> 6);
  int l = threadIdx.x & 63;
  const float* ip = x1 + (size_t)tok * DM;
  float tv[32]; float ss = 0.f;
#pragma unroll
  for (int i = 0; i < 32; i++) { float v = ip[l + i*64]; tv[i] = v; ss += v*v; }
#pragma unroll
  for (int off = 32; off > 0; off >>= 1) ss += __shfl_xor(ss, off);
  float rn = rsqrtf(ss * (1.f/DM) + 1e-6f);
  float acc[8];
#pragma unroll
  for (int e = 0; e < 8; e++) acc[e] = 0.f;
#pragma unroll
  for (int i = 0; i < 32; i++) {
    int d = l + i*64;
    float tval = tv[i]*rn*w2[d];
#pragma unroll
    for (int e = 0; e < 8; e++) acc[e] += tval * rw[d*8 + e];
  }
#pragma unroll
  for (int e = 0; e < 8; e++)
#pragma unroll
    for (int off = 32; off > 0; off >>= 1) acc[e] += __shfl_xor(acc[e], off);
  if (l == 0) {
    float sig[8], scv[8];
#pragma unroll
    for (int e = 0; e < 8; e++) { sig[e] = 1.f/(1.f + expf(-acc[e])); scv[e] = sig[e] + rb[e]; }
    int i0 = 0;
#pragma unroll
    for (int e = 1; e < 8; e++) if (scv[e] > scv[i0]) i0 = e;
    int i1 = (i0 == 0) ? 1 : 0;
#pragma unroll
    for (int e = 0; e < 8; e++) if (e != i0 && scv[e] > scv[i1]) i1 = e;
    float a0 = sig[i0], a1 = sig[i1], inv = 1.f/(a0 + a1);
    top_i[tok] = i0 | (i1 << 8);
    top_w[tok*2]   = a0*inv;
    top_w[tok*2+1] = a1*inv;
  }
}

// ---------------- build per-expert lists + row-block schedule (1 block) ----------------
__global__ __launch_bounds__(256)
void build_k(const int* __restrict__ top_i, const float* __restrict__ top_w,
             int* __restrict__ cnt, int* __restrict__ blk_e, int* __restrict__ blk_r0,
             int* __restrict__ total_nblk, int* __restrict__ idxlist, float* __restrict__ wlist)
{
  __shared__ int lcnt[8];
  int tid = threadIdx.x;
  if (tid < 8) lcnt[tid] = 0;
  __syncthreads();
  for (int t = tid; t < SD; t += 256) {
    int pk = top_i[t];
    int i0 = pk & 0xFF, i1 = (pk >> 8) & 0xFF;
    int p0 = atomicAdd(&lcnt[i0], 1);
    idxlist[i0*2048 + p0] = t;             // rank 0
    wlist [i0*2048 + p0] = top_w[t*2];
    int p1 = atomicAdd(&lcnt[i1], 1);
    idxlist[i1*2048 + p1] = t | (1 << 16); // rank 1
    wlist [i1*2048 + p1] = top_w[t*2+1];
  }
  __syncthreads();
  if (tid < 8) cnt[tid] = lcnt[tid];
  if (tid == 0) {
    int tot = 0;
    for (int e = 0; e < 8; e++) {
      int nb = (lcnt[e] + 127) >> 7;
      for (int b = 0; b < nb; b++) { blk_e[tot] = e; blk_r0[tot] = b*128; tot++; }
    }
    *total_nblk = tot;
  }
}

// ---------------- out = x1 + tmp0 + tmp1 ----------------
__global__ __launch_bounds__(256)
void final_add(const float* __restrict__ x1, const bf16* __restrict__ t0,
               const bf16* __restrict__ t1, float* __restrict__ out)
{
  size_t i = ((size_t)blockIdx.x*256 + threadIdx.x) * 4;
  f32x4 a = *(const f32x4*)(x1 + i);
  bf16x4 b0 = *(const bf16x4*)(t0 + i);
  bf16x4 b1 = *(const bf16x4*)(t1 + i);
  f32x4 o;
#pragma unroll
  for (int j = 0; j < 4; j++) o[j] = a[j] + (float)b0[j] + (float)b1[j];
  *(f32x4*)(out + i) = o;
}

// ---------------- flash attention: causal GQA, 64-row q tiles, 4 waves ----------------
__global__ __launch_bounds__(256)
void flash(const bf16* __restrict__ qb, const bf16* __restrict__ kb,
           const bf16* __restrict__ vtb, bf16* __restrict__ ob)
{
  __shared__ __align__(16) bf16 Ks[64*128];   // [kv][d], XOR-swizzled 16B blocks
  __shared__ __align__(16) bf16 Vs[128*64];   // [d][kv], XOR-swizzled
  __shared__ __align__(16) bf16 Ps[4*16*64];  // per-wave P tiles, XOR-swizzled
  const int tid = threadIdx.x, wv = tid >> 6, l = tid & 63;
  const int qt = blockIdx.x, h = blockIdx.y, g = h >> 2;

  const int qrow = qt*64 + wv*16 + (l & 15);
  bf16x8 qf[4];
#pragma unroll
  for (int f = 0; f < 4; f++)
    qf[f] = *(const bf16x8*)(qb + ((size_t)h*SD + qrow)*DHD + f*32 + (l >> 4)*8);

  float mrun[4], lrun[4];
#pragma unroll
  for (int r = 0; r < 4; r++) { mrun[r] = -1e30f; lrun[r] = 0.f; }
  f32x4 oac[8];
  const f32x4 vz = {0.f, 0.f, 0.f, 0.f};
#pragma unroll
  for (int d = 0; d < 8; d++) oac[d] = vz;

  for (int j = 0; j <= qt; ++j) {
#pragma unroll
    for (int c = 0; c < 4; c++) {
      int chunk = wv*4 + c;
      int rk = chunk*4 + (l >> 4);
      int ck = (l & 15) ^ (rk & 7);                       // pre-swizzled global source
      async16(&Ks[chunk*512], kb + ((size_t)g*SD + j*64 + rk)*DHD + ck*8);
      int rv = chunk*8 + (l >> 3);
      int cv = (l & 7) ^ (rv & 7);
      async16(&Vs[chunk*512], vtb + ((size_t)g*DHD + rv)*SD + j*64 + cv*8);
    }
    __syncthreads();

    f32x4 sf[4];
#pragma unroll
    for (int n = 0; n < 4; n++) sf[n] = vz;
#pragma unroll
    for (int f = 0; f < 4; f++) {
#pragma unroll
      for (int n = 0; n < 4; n++) {
        int row = n*16 + (l & 15);
        int cb = (f*64 + (l >> 4)*16) ^ ((row & 7) << 4);
        bf16x8 kf = *(const bf16x8*)((const char*)Ks + row*256 + cb);
        sf[n] = __builtin_amdgcn_mfma_f32_16x16x32_bf16(qf[f], kf, sf[n], 0, 0, 0);
      }
    }
    if (j == qt) {
#pragma unroll
      for (int n = 0; n < 4; n++)
#pragma unroll
        for (int r = 0; r < 4; r++) {
          int kvp = n*16 + (l & 15);
          int qp  = wv*16 + (l >> 4)*4 + r;
          if (kvp > qp) sf[n][r] = -1e30f;
        }
    }
    // online softmax (row spread over 16-lane group; each lane owns 4 q-rows r)
#pragma unroll
    for (int r = 0; r < 4; r++) {
      float tm = fmaxf(fmaxf(sf[0][r], sf[1][r]), fmaxf(sf[2][r], sf[3][r]));
#pragma unroll
      for (int off = 8; off > 0; off >>= 1) tm = fmaxf(tm, __shfl_xor(tm, off));
      float mn = fmaxf(mrun[r], tm);
      float fac = __expf(mrun[r] - mn);
      mrun[r] = mn;
      float pe[4]; float ps = 0.f;
#pragma unroll
      for (int n = 0; n < 4; n++) { pe[n] = __expf(sf[n][r] - mn); ps += pe[n]; }
#pragma unroll
      for (int off = 8; off > 0; off >>= 1) ps += __shfl_xor(ps, off);
      lrun[r] = lrun[r]*fac + ps;
#pragma unroll
      for (int d = 0; d < 8; d++) oac[d][r] *= fac;
      int prow = (l >> 4)*4 + r;
#pragma unroll
      for (int n = 0; n < 4; n++) {
        int cbp = ((n*16 + (l & 15))*2) ^ ((prow & 7) << 4);
        *(bf16*)((char*)Ps + wv*2048 + prow*128 + cbp) = (bf16)pe[n];
      }
    }
    // PV
#pragma unroll
    for (int ks = 0; ks < 2; ks++) {
      int pr = l & 15;
      int cbp = (ks*64 + (l >> 4)*16) ^ ((pr & 7) << 4);
      bf16x8 pa = *(const bf16x8*)((const char*)Ps + wv*2048 + pr*128 + cbp);
#pragma unroll
      for (int dt = 0; dt < 8; dt++) {
        int rv = dt*16 + (l & 15);
        int cbv = (ks*64 + (l >> 4)*16) ^ ((rv & 7) << 4);
        bf16x8 vf = *(const bf16x8*)((const char*)Vs + rv*128 + cbv);
        oac[dt] = __builtin_amdgcn_mfma_f32_16x16x32_bf16(pa, vf, oac[dt], 0, 0, 0);
      }
    }
    __syncthreads();
  }
#pragma unroll
  for (int dt = 0; dt < 8; dt++)
#pragma unroll
    for (int r = 0; r < 4; r++) {
      int s = qt*64 + wv*16 + (l >> 4)*4 + r;
      int d = dt*16 + (l & 15);
      ob[(size_t)s*DM + h*DHD + d] = (bf16)(oac[dt][r] / lrun[r]);
    }
}

// ---------------- launch ----------------
extern "C" void kernel_launch(void* const* d_in, const int* in_sizes, int n_in,
                              void* d_out, int out_size, void* d_ws, size_t ws_size,
                              hipStream_t stream) {
  if (ws_size < WS_NEED) return;  // fail loudly (out stays poisoned)
  const float* x     = (const float*)d_in[0];
  const float* ln1_w = (const float*)d_in[1];
  const float* ln2_w = (const float*)d_in[2];
  const float* wq    = (const float*)d_in[3];
  const float* wk    = (const float*)d_in[4];
  const float* wv    = (const float*)d_in[5];
  const float* wo    = (const float*)d_in[6];
  const float* qnw   = (const float*)d_in[7];
  const float* knw   = (const float*)d_in[8];
  const float* rw    = (const float*)d_in[9];
  const float* rb    = (const float*)d_in[10];
  const float* wg    = (const float*)d_in[11];
  const float* wu    = (const float*)d_in[12];
  const float* wd    = (const float*)d_in[13];

  char* ws = (char*)d_ws;
  bf16*  wqkvT = (bf16*)(ws + OF_WQKVT);
  bf16*  wguT  = (bf16*)(ws + OF_WGUT);
  bf16*  wdT   = (bf16*)(ws + OF_WDT);
  bf16*  woT   = (bf16*)(ws + OF_WOT);
  bf16*  hb    = (bf16*)(ws + OF_H);
  float* qkvf  = (float*)(ws + OF_QKV);
  bf16*  qbb   = (bf16*)(ws + OF_QB);
  bf16*  kbb   = (bf16*)(ws + OF_KB);
  bf16*  vtbb  = (bf16*)(ws + OF_VTB);
  float* x1f   = (float*)(ws + OF_X1);
  bf16*  actb  = (bf16*)(ws + OF_ACT);
  bf16*  tbb   = (bf16*)(ws + OF_TB);
  bf16*  obb   = (bf16*)(ws + OF_OB);
  int*   cntp  = (int*)(ws + OF_CNT);
  int*   blke  = (int*)(ws + OF_BLKE);
  int*   blkr  = (int*)(ws + OF_BLKR);
  int*   totp  = (int*)(ws + OF_TOT);
  int*   topi  = (int*)(ws + OF_TOPI);
  float* topw  = (float*)(ws + OF_TOPW);
  int*   idxl  = (int*)(ws + OF_IDXL);
  float* wlst  = (float*)(ws + OF_WLST);
  bf16*  tmp0  = (bf16*)(ws + OF_TMP0);
  bf16*  tmp1  = (bf16*)(ws + OF_TMP1);
  float* outp  = (float*)d_out;

  dim3 b32(32, 8);
  // weight transposes (f32 [K][N] -> bf16 [N][K])
  transpose_cvt<<<dim3(64,64,1), b32, 0, stream>>>(wq, 2048, 0, wqkvT, 2048, 0, 1, 0);
  transpose_cvt<<<dim3(16,64,1), b32, 0, stream>>>(wk,  512, 0, wqkvT, 2048, 0, 1, 2048);
  transpose_cvt<<<dim3(16,64,1), b32, 0, stream>>>(wv,  512, 0, wqkvT, 2048, 0, 1, 2560);
  transpose_cvt<<<dim3(64,64,1), b32, 0, stream>>>(wo, 2048, 0, woT,   2048, 0, 1, 0);
  transpose_cvt<<<dim3(32,64,8), b32, 0, stream>>>(wg, 1024, 2048ll*1024, wguT, 2048, 2048ll*2048, 2, 0);
  transpose_cvt<<<dim3(32,64,8), b32, 0, stream>>>(wu, 1024, 2048ll*1024, wguT, 2048, 2048ll*2048, 2, 1);
  transpose_cvt<<<dim3(64,32,8), b32, 0, stream>>>(wd, 2048, 1024ll*2048, wdT,  1024, 2048ll*1024, 1, 0);

  rmsnorm_k<<<2048, 256, 0, stream>>>(x, ln1_w, hb);
  gemm_bt<0><<<dim3(24,16,1), 256, 0, stream>>>(hb, wqkvT, qkvf, nullptr, 2048, 3072, 2048);
  qrope_k<<<2048, 256, 0, stream>>>(qkvf, qnw, qbb);
  krope_k<<<2048, 128, 0, stream>>>(qkvf, knw, kbb);
  transpose_cvt<<<dim3(16,64,1), b32, 0, stream>>>(qkvf + 2560, 3072, 0, vtbb, 2048, 0, 1, 0);

  flash<<<dim3(32,16,1), 256, 0, stream>>>(qbb, kbb, vtbb, obb);

  gemm_bt<1><<<dim3(16,16,1), 256, 0, stream>>>(obb, woT, x1f, x, 2048, 2048, 2048);
  rmsnorm_k<<<2048, 256, 0, stream>>>(x1f, ln2_w, tbb);
  router_k<<<512, 256, 0, stream>>>(x1f, ln2_w, rw, rb, topi, topw);
  build_k<<<1, 256, 0, stream>>>(topi, topw, cntp, blke, blkr, totp, idxl, wlst);

  // sparse MoE: only routed (token, expert) pairs are computed
  gemm_moe_gu<<<dim3(16,40,1), 256, 0, stream>>>(tbb, wguT, actb, cntp, blke, blkr, totp, idxl);
  gemm_moe_dn<<<dim3(16,40,1), 256, 0, stream>>>(actb, wdT, tmp0, tmp1, cntp, blke, blkr, totp, idxl, wlst);
  final_add<<<4096, 256, 0, stream>>>(x1f, tmp0, tmp1, outp);
}

// Round 3
// 621.636 us; speedup vs baseline: 1.4833x; 1.0140x over previous
//
#include <hip/hip_runtime.h>
#include <hip/hip_bf16.h>
#include <stdint.h>
#include <math.h>

typedef __bf16 bf16;
typedef __bf16 bf16x8 __attribute__((ext_vector_type(8)));
typedef __bf16 bf16x4 __attribute__((ext_vector_type(4)));
typedef float  f32x4  __attribute__((ext_vector_type(4)));

#define SD 2048      // sequence length
#define DM 2048      // model dim
#define NH 16        // heads
#define NKV 4        // kv heads
#define DHD 128      // head dim
#define NE 8         // experts
#define NNI 1024     // expert intermediate

// ---------------- workspace layout (bytes) ----------------
constexpr size_t OF_WQKVT = 0;                        // bf16 [3072][2048]
constexpr size_t OF_WGUT  = OF_WQKVT + 12582912ull;   // bf16 [8][2048][2048] (gate/up interleaved rows)
constexpr size_t OF_WDT   = OF_WGUT  + 67108864ull;   // bf16 [8][2048][1024]
constexpr size_t OF_WOT   = OF_WDT   + 33554432ull;   // bf16 [2048][2048]   (tb, tmp1 alias later)
constexpr size_t OF_H     = OF_WOT   + 8388608ull;    // bf16 [2048][2048]   (ob, tmp0 alias later)
constexpr size_t OF_QKV   = OF_H     + 8388608ull;    // f32  [2048][3072]
constexpr size_t OF_QB    = OF_QKV   + 25165824ull;   // bf16 [16][2048][128]
constexpr size_t OF_KB    = OF_QB    + 8388608ull;    // bf16 [4][2048][128] (router scratch aliases later)
constexpr size_t OF_VTB   = OF_KB    + 2097152ull;    // bf16 [4][128][2048]
constexpr size_t OF_X1    = OF_VTB   + 2097152ull;    // f32  [2048][2048]  (rope table aliases EARLY: x1 written only at o-proj)
constexpr size_t WS_NEED  = OF_X1    + 16777216ull;   // 184,549,376 B
// aliases (regions dead by the time these are written):
constexpr size_t OF_ACT  = OF_QKV;          // bf16 [8][2048][1024] (== QKV+QB span, dead after flash)
constexpr size_t OF_TB   = OF_WOT;          // bf16 [2048][2048] (woT dead after o-proj)
constexpr size_t OF_OB   = OF_H;            // bf16 [2048][2048] (h dead after qkv gemm)
constexpr size_t OF_ROPET= OF_X1;           // float [2048][32][2] = 512KB (x1 written later)
// router/scheduler scratch inside OF_KB (k-cache dead after flash):
constexpr size_t OF_CNT  = OF_KB;           // int [8]
constexpr size_t OF_BLKE = OF_KB + 512;     // int [128]
constexpr size_t OF_BLKR = OF_KB + 1024;    // int [128]
constexpr size_t OF_TOT  = OF_KB + 1536;    // int [1]
constexpr size_t OF_TOPI = OF_KB + 2048;    // int [2048]
constexpr size_t OF_TOPW = OF_KB + 16384;   // float [2048][2]
constexpr size_t OF_IDXL = OF_KB + 65536;   // int [8][2048]
constexpr size_t OF_WLST = OF_KB + 131072;  // float [8][2048]
constexpr size_t OF_TMP0 = OF_H;            // bf16 [2048][2048] (ob dead after o-proj)
constexpr size_t OF_TMP1 = OF_WOT;          // bf16 [2048][2048] (tb dead after gate/up)

// ---------------- async global->LDS (16B/lane, wave-uniform LDS base) ----------------
__device__ __forceinline__ void async16(void* lds, const void* g) {
  uint32_t lo = (uint32_t)(uintptr_t)lds;
  __builtin_amdgcn_global_load_lds(
      (const __attribute__((address_space(1))) uint32_t*)(uintptr_t)g,
      (__attribute__((address_space(3))) uint32_t*)lo,
      16, 0, 0);
}

// ---------------- generic f32 [R][C] -> bf16 [C*ost+oroff][R] transpose+convert ----------------
__global__ void transpose_cvt(const float* __restrict__ in, int ild, long long inb,
                              bf16* __restrict__ out, int old_, long long outb,
                              int ost, int oroff)
{
  __shared__ float tile[32][33];
  const float* ip = in + (long long)blockIdx.z * inb;
  bf16* op = out + (long long)blockIdx.z * outb;
  int r0 = blockIdx.y * 32, c0 = blockIdx.x * 32;
  int tx = threadIdx.x, ty = threadIdx.y; // 32 x 8
#pragma unroll
  for (int i = 0; i < 4; i++)
    tile[ty + i*8][tx] = ip[(size_t)(r0 + ty + i*8)*ild + c0 + tx];
  __syncthreads();
#pragma unroll
  for (int i = 0; i < 4; i++) {
    int cl = ty + i*8;
    op[(size_t)((c0 + cl)*ost + oroff)*old_ + r0 + tx] = (bf16)tile[tx][cl];
  }
}

// ---------------- rope cos/sin table: tab[s][fi] = {cos, sin} of s*theta^(-fi/32) ----------------
__global__ __launch_bounds__(256)
void rope_tab_k(float* __restrict__ tab)
{
  int i = blockIdx.x*256 + threadIdx.x;   // 65536 = 2048*32
  int s = i >> 5, fi = i & 31;
  float ang = (float)s * expf(-(float)fi * (13.815510557964274f/32.f)); // theta=1e6
  float c, sn; sincosf(ang, &sn, &c);
  tab[i*2]   = c;
  tab[i*2+1] = sn;
}

// ---------------- rmsnorm f32 [S][2048] -> bf16 ----------------
__global__ __launch_bounds__(256)
void rmsnorm_k(const float* __restrict__ in, const float* __restrict__ w, bf16* __restrict__ outb)
{
  __shared__ float red[4];
  int s = blockIdx.x, t = threadIdx.x;
  const float* ip = in + (size_t)s * DM;
  float v[8]; float ss = 0.f;
#pragma unroll
  for (int i = 0; i < 8; i++) { v[i] = ip[t + i*256]; ss += v[i]*v[i]; }
#pragma unroll
  for (int off = 32; off > 0; off >>= 1) ss += __shfl_xor(ss, off);
  if ((t & 63) == 0) red[t >> 6] = ss;
  __syncthreads();
  float rn = rsqrtf((red[0]+red[1]+red[2]+red[3]) * (1.f/DM) + 1e-6f);
  bf16* op = outb + (size_t)s * DM;
#pragma unroll
  for (int i = 0; i < 8; i++) op[t + i*256] = (bf16)(v[i]*rn*w[t + i*256]);
}

// ---------------- q: rmsnorm(2048) + rope + 1/sqrt(DH), write [H][S][128] bf16 ----------------
__global__ __launch_bounds__(256)
void qrope_k(const float* __restrict__ qkv, const float* __restrict__ w,
             const float* __restrict__ tab, bf16* __restrict__ qout)
{
  __shared__ float row[2048];
  __shared__ float red[4];
  int s = blockIdx.x, t = threadIdx.x;
  const float* ip = qkv + (size_t)s * 3072;
  const float2* tab2 = (const float2*)tab;
  float ss = 0.f;
#pragma unroll
  for (int i = 0; i < 8; i++) { float x = ip[t + i*256]; row[t + i*256] = x; ss += x*x; }
#pragma unroll
  for (int off = 32; off > 0; off >>= 1) ss += __shfl_xor(ss, off);
  if ((t & 63) == 0) red[t >> 6] = ss;
  __syncthreads();
  float rn = rsqrtf((red[0]+red[1]+red[2]+red[3]) * (1.f/2048.f) + 1e-6f);
  const float sc = 0.08838834764831845f; // 1/sqrt(128)
#pragma unroll
  for (int i = 0; i < 8; i++) {
    int idx = t + i*256;
    int d = idx & 127;
    float val = row[idx]*rn*w[idx];
    float o;
    if (d < 64) {
      int fi = d & 31;
      float2 cs = tab2[s*32 + fi];
      float pv = row[idx ^ 32]*rn*w[idx ^ 32];
      o = (d < 32) ? (val*cs.x - pv*cs.y) : (val*cs.x + pv*cs.y);
    } else o = val;
    qout[((size_t)(idx >> 7)*SD + s)*DHD + d] = (bf16)(o * sc);
  }
}

// ---------------- k: rmsnorm(512) + rope, write [KV][S][128] bf16 ----------------
__global__ __launch_bounds__(128)
void krope_k(const float* __restrict__ qkv, const float* __restrict__ w,
             const float* __restrict__ tab, bf16* __restrict__ kout)
{
  __shared__ float row[512];
  __shared__ float red[2];
  int s = blockIdx.x, t = threadIdx.x;
  const float* ip = qkv + (size_t)s * 3072 + 2048;
  const float2* tab2 = (const float2*)tab;
  float ss = 0.f;
#pragma unroll
  for (int i = 0; i < 4; i++) { float x = ip[t + i*128]; row[t + i*128] = x; ss += x*x; }
#pragma unroll
  for (int off = 32; off > 0; off >>= 1) ss += __shfl_xor(ss, off);
  if ((t & 63) == 0) red[t >> 6] = ss;
  __syncthreads();
  float rn = rsqrtf((red[0]+red[1]) * (1.f/512.f) + 1e-6f);
#pragma unroll
  for (int i = 0; i < 4; i++) {
    int idx = t + i*128;
    int d = idx & 127;
    float val = row[idx]*rn*w[idx];
    float o;
    if (d < 64) {
      int fi = d & 31;
      float2 cs = tab2[s*32 + fi];
      float pv = row[idx ^ 32]*rn*w[idx ^ 32];
      o = (d < 32) ? (val*cs.x - pv*cs.y) : (val*cs.x + pv*cs.y);
    } else o = val;
    kout[((size_t)(idx >> 7)*SD + s)*DHD + d] = (bf16)o;
  }
}

// ---------------- GEMM: C[M][N] = A(bf16 [M][K]) @ BT(bf16 [N][K])^T, tile BM x 128 ----------------
// EPI 0: C f32 plain    1: C = acc + res
template<int EPI, int BM>
__global__ __launch_bounds__(256)
void gemm_bt(const bf16* __restrict__ Ag, const bf16* __restrict__ Bg,
             float* __restrict__ Cg, const float* __restrict__ res,
             int M, int N, int K)
{
  constexpr int WM  = BM/2;          // rows per wave
  constexpr int MI  = WM/16;         // m-fragments per wave
  constexpr int NCH = (BM+128)/16;   // 1KB staging chunks ([A;B] stacked)
  constexpr int CPW = NCH/4;
  __shared__ __align__(16) bf16 As[2][BM*32];
  __shared__ __align__(16) bf16 Bs[2][128*32];
  const int tid = threadIdx.x;
  const int wv = tid >> 6, l = tid & 63;
  const int wm = wv >> 1, wn = wv & 1;
  const int bm = blockIdx.y * BM, bn = blockIdx.x * 128;
  const bf16* A  = Ag;
  const bf16* BT = Bg;

  f32x4 acc[MI][4];
  const f32x4 vz = {0.f, 0.f, 0.f, 0.f};
#pragma unroll
  for (int i = 0; i < MI; i++)
#pragma unroll
    for (int j = 0; j < 4; j++) acc[i][j] = vz;

  auto stage = [&](int kt, int b) {
    int k0 = kt * 32;
    int kc = (l & 3) * 8;
#pragma unroll
    for (int c = 0; c < CPW; c++) {
      int chunk = wv*CPW + c;
      int row = chunk*16 + (l >> 2);
      if (chunk < BM/16)
        async16(&As[b][chunk*512], A  + (size_t)(bm + row)*K + k0 + kc);
      else
        async16(&Bs[b][(chunk - BM/16)*512], BT + (size_t)(bn + row - BM)*K + k0 + kc);
    }
  };

  int nkt = K >> 5;
  stage(0, 0);
  int buf = 0;
  for (int kt = 0; kt < nkt; ++kt) {
    __syncthreads();                    // drains vmcnt -> staged tile visible
    if (kt + 1 < nkt) stage(kt + 1, buf ^ 1);
    bf16x8 af[MI], bfv[4];
#pragma unroll
    for (int m = 0; m < MI; m++)
      af[m] = *(const bf16x8*)&As[buf][(wm*WM + m*16 + (l & 15))*32 + (l >> 4)*8];
#pragma unroll
    for (int n = 0; n < 4; n++)
      bfv[n] = *(const bf16x8*)&Bs[buf][(wn*64 + n*16 + (l & 15))*32 + (l >> 4)*8];
#pragma unroll
    for (int m = 0; m < MI; m++)
#pragma unroll
      for (int n = 0; n < 4; n++)
        acc[m][n] = __builtin_amdgcn_mfma_f32_16x16x32_bf16(af[m], bfv[n], acc[m][n], 0, 0, 0);
    buf ^= 1;
  }

#pragma unroll
  for (int m = 0; m < MI; m++) {
#pragma unroll
    for (int n = 0; n < 4; n++) {
#pragma unroll
      for (int r = 0; r < 4; r++) {
        int row = bm + wm*WM + m*16 + (l >> 4)*4 + r;
        int col = bn + wn*64 + n*16 + (l & 15);
        float v = acc[m][n][r];
        if (EPI == 0) {
          Cg[(size_t)row*N + col] = v;
        } else {
          Cg[(size_t)row*N + col] = v + res[(size_t)row*N + col];
        }
      }
    }
  }
}

// ---------------- MoE gate/up GEMM: 64-row gathered blocks, silu(gate)*up epilogue ----------------
__global__ __launch_bounds__(256)
void gemm_moe_gu(const bf16* __restrict__ tb, const bf16* __restrict__ wgu,
                 bf16* __restrict__ act,
                 const int* __restrict__ cnt, const int* __restrict__ blk_e,
                 const int* __restrict__ blk_r0, const int* __restrict__ total_nblk,
                 const int* __restrict__ idxlist)
{
  const int by = blockIdx.y;
  if (by >= *total_nblk) return;
  const int e = blk_e[by], r0 = blk_r0[by], cn = cnt[e];
  __shared__ __align__(16) bf16 As[2][64*32];
  __shared__ __align__(16) bf16 Bs[2][128*32];
  const int tid = threadIdx.x;
  const int wv = tid >> 6, l = tid & 63;
  const int wm = wv >> 1, wn = wv & 1;
  const int bn = blockIdx.x * 128;
  const bf16* BT = wgu + (size_t)e*2048*2048;

  // gathered A row pointers (K-loop invariant); chunks 0..3 are A (12 chunks total, 3/wave)
  const bf16* Aptr[3];
#pragma unroll
  for (int c = 0; c < 3; c++) {
    int chunk = wv*3 + c;
    Aptr[c] = tb;
    if (chunk < 4) {
      int rp = r0 + chunk*16 + (l >> 2);
      int tok = (rp < cn) ? (idxlist[e*2048 + rp] & 0xFFFF) : 0;
      Aptr[c] = tb + (size_t)tok*2048 + (l & 3)*8;
    }
  }

  f32x4 acc[2][4];
  const f32x4 vz = {0.f, 0.f, 0.f, 0.f};
#pragma unroll
  for (int i = 0; i < 2; i++)
#pragma unroll
    for (int j = 0; j < 4; j++) acc[i][j] = vz;

  auto stage = [&](int kt, int b) {
    int k0 = kt * 32;
    int kc = (l & 3) * 8;
#pragma unroll
    for (int c = 0; c < 3; c++) {
      int chunk = wv*3 + c;
      if (chunk < 4)
        async16(&As[b][chunk*512], Aptr[c] + k0);
      else {
        int row = chunk*16 + (l >> 2) - 64;
        async16(&Bs[b][(chunk-4)*512], BT + (size_t)(bn + row)*2048 + k0 + kc);
      }
    }
  };

  stage(0, 0);
  int buf = 0;
  for (int kt = 0; kt < 64; ++kt) {
    __syncthreads();
    if (kt + 1 < 64) stage(kt + 1, buf ^ 1);
    bf16x8 af[2], bfv[4];
#pragma unroll
    for (int m = 0; m < 2; m++)
      af[m] = *(const bf16x8*)&As[buf][(wm*32 + m*16 + (l & 15))*32 + (l >> 4)*8];
#pragma unroll
    for (int n = 0; n < 4; n++)
      bfv[n] = *(const bf16x8*)&Bs[buf][(wn*64 + n*16 + (l & 15))*32 + (l >> 4)*8];
#pragma unroll
    for (int m = 0; m < 2; m++)
#pragma unroll
      for (int n = 0; n < 4; n++)
        acc[m][n] = __builtin_amdgcn_mfma_f32_16x16x32_bf16(af[m], bfv[n], acc[m][n], 0, 0, 0);
    buf ^= 1;
  }

  bf16* ap = act + (size_t)e*2048*1024;
#pragma unroll
  for (int m = 0; m < 2; m++) {
#pragma unroll
    for (int n = 0; n < 4; n++) {
#pragma unroll
      for (int r = 0; r < 4; r++) {
        int lrow = wm*32 + m*16 + (l >> 4)*4 + r;
        int col = bn + wn*64 + n*16 + (l & 15);
        float v = acc[m][n][r];
        float p = __shfl_xor(v, 1);        // partner column (gate<->up pair)
        if (!(l & 1)) {
          float a = v / (1.f + __expf(-v)) * p;   // silu(gate)*up
          ap[(size_t)(r0 + lrow)*1024 + (col >> 1)] = (bf16)a;
        }
      }
    }
  }
}

// ---------------- MoE down GEMM: 64-row blocks, scatter w*acc to rank-indexed tmp buffers ----------------
__global__ __launch_bounds__(256)
void gemm_moe_dn(const bf16* __restrict__ act, const bf16* __restrict__ wdt,
                 bf16* __restrict__ tmp0, bf16* __restrict__ tmp1,
                 const int* __restrict__ cnt, const int* __restrict__ blk_e,
                 const int* __restrict__ blk_r0, const int* __restrict__ total_nblk,
                 const int* __restrict__ idxlist, const float* __restrict__ wlist)
{
  const int by = blockIdx.y;
  if (by >= *total_nblk) return;
  const int e = blk_e[by], r0 = blk_r0[by], cn = cnt[e];
  __shared__ __align__(16) bf16 As[2][64*32];
  __shared__ __align__(16) bf16 Bs[2][128*32];
  const int tid = threadIdx.x;
  const int wv = tid >> 6, l = tid & 63;
  const int wm = wv >> 1, wn = wv & 1;
  const int bn = blockIdx.x * 128;
  const bf16* A  = act + (size_t)e*2048*1024 + (size_t)r0*1024;
  const bf16* BT = wdt + (size_t)e*2048*1024;

  f32x4 acc[2][4];
  const f32x4 vz = {0.f, 0.f, 0.f, 0.f};
#pragma unroll
  for (int i = 0; i < 2; i++)
#pragma unroll
    for (int j = 0; j < 4; j++) acc[i][j] = vz;

  auto stage = [&](int kt, int b) {
    int k0 = kt * 32;
    int kc = (l & 3) * 8;
#pragma unroll
    for (int c = 0; c < 3; c++) {
      int chunk = wv*3 + c;
      int row = chunk*16 + (l >> 2);
      if (chunk < 4)
        async16(&As[b][chunk*512], A  + (size_t)row*1024 + k0 + kc);
      else
        async16(&Bs[b][(chunk-4)*512], BT + (size_t)(bn + row - 64)*1024 + k0 + kc);
    }
  };

  stage(0, 0);
  int buf = 0;
  for (int kt = 0; kt < 32; ++kt) {
    __syncthreads();
    if (kt + 1 < 32) stage(kt + 1, buf ^ 1);
    bf16x8 af[2], bfv[4];
#pragma unroll
    for (int m = 0; m < 2; m++)
      af[m] = *(const bf16x8*)&As[buf][(wm*32 + m*16 + (l & 15))*32 + (l >> 4)*8];
#pragma unroll
    for (int n = 0; n < 4; n++)
      bfv[n] = *(const bf16x8*)&Bs[buf][(wn*64 + n*16 + (l & 15))*32 + (l >> 4)*8];
#pragma unroll
    for (int m = 0; m < 2; m++)
#pragma unroll
      for (int n = 0; n < 4; n++)
        acc[m][n] = __builtin_amdgcn_mfma_f32_16x16x32_bf16(af[m], bfv[n], acc[m][n], 0, 0, 0);
    buf ^= 1;
  }

#pragma unroll
  for (int m = 0; m < 2; m++) {
#pragma unroll
    for (int n = 0; n < 4; n++) {
#pragma unroll
      for (int r = 0; r < 4; r++) {
        int lrow = wm*32 + m*16 + (l >> 4)*4 + r;
        int rie = r0 + lrow;
        if (rie < cn) {
          int col = bn + wn*64 + n*16 + (l & 15);
          int pk = idxlist[e*2048 + rie];
          int t = pk & 0xFFFF, rank = pk >> 16;
          float w = wlist[e*2048 + rie];
          bf16* dst = rank ? tmp1 : tmp0;
          dst[(size_t)t*2048 + col] = (bf16)(w * acc[m][n][r]);
        }
      }
    }
  }
}

// ---------------- router: f32 path from x1 (own rmsnorm), sigmoid top-2 per token ----------------
__global__ __launch_bounds__(256)
void router_k(const float* __restrict__ x1, const float* __restrict__ w2,
              const float* __restrict__ rw, const float* __restrict__ rb,
              int* __restrict__ top_i, float* __restrict__ top_w)
{
  int tok = blockIdx.x*4 + (threadIdx.x >> 6);
  int l = threadIdx.x & 63;
  const float* ip = x1 + (size_t)tok * DM;
  float tv[32]; float ss = 0.f;
#pragma unroll
  for (int i = 0; i < 32; i++) { float v = ip[l + i*64]; tv[i] = v; ss += v*v; }
#pragma unroll
  for (int off = 32; off > 0; off >>= 1) ss += __shfl_xor(ss, off);
  float rn = rsqrtf(ss * (1.f/DM) + 1e-6f);
  float acc[8];
#pragma unroll
  for (int e = 0; e < 8; e++) acc[e] = 0.f;
#pragma unroll
  for (int i = 0; i < 32; i++) {
    int d = l + i*64;
    float tval = tv[i]*rn*w2[d];
#pragma unroll
    for (int e = 0; e < 8; e++) acc[e] += tval * rw[d*8 + e];
  }
#pragma unroll
  for (int e = 0; e < 8; e++)
#pragma unroll
    for (int off = 32; off > 0; off >>= 1) acc[e] += __shfl_xor(acc[e], off);
  if (l == 0) {
    float sig[8], scv[8];
#pragma unroll
    for (int e = 0; e < 8; e++) { sig[e] = 1.f/(1.f + expf(-acc[e])); scv[e] = sig[e] + rb[e]; }
    int i0 = 0;
#pragma unroll
    for (int e = 1; e < 8; e++) if (scv[e] > scv[i0]) i0 = e;
    int i1 = (i0 == 0) ? 1 : 0;
#pragma unroll
    for (int e = 0; e < 8; e++) if (e != i0 && scv[e] > scv[i1]) i1 = e;
    float a0 = sig[i0], a1 = sig[i1], inv = 1.f/(a0 + a1);
    top_i[tok] = i0 | (i1 << 8);
    top_w[tok*2]   = a0*inv;
    top_w[tok*2+1] = a1*inv;
  }
}

// ---------------- build per-expert lists + 64-row block schedule (1 block) ----------------
__global__ __launch_bounds__(256)
void build_k(const int* __restrict__ top_i, const float* __restrict__ top_w,
             int* __restrict__ cnt, int* __restrict__ blk_e, int* __restrict__ blk_r0,
             int* __restrict__ total_nblk, int* __restrict__ idxlist, float* __restrict__ wlist)
{
  __shared__ int lcnt[8];
  int tid = threadIdx.x;
  if (tid < 8) lcnt[tid] = 0;
  __syncthreads();
  for (int t = tid; t < SD; t += 256) {
    int pk = top_i[t];
    int i0 = pk & 0xFF, i1 = (pk >> 8) & 0xFF;
    int p0 = atomicAdd(&lcnt[i0], 1);
    idxlist[i0*2048 + p0] = t;             // rank 0
    wlist [i0*2048 + p0] = top_w[t*2];
    int p1 = atomicAdd(&lcnt[i1], 1);
    idxlist[i1*2048 + p1] = t | (1 << 16); // rank 1
    wlist [i1*2048 + p1] = top_w[t*2+1];
  }
  __syncthreads();
  if (tid < 8) cnt[tid] = lcnt[tid];
  if (tid == 0) {
    int tot = 0;
    for (int e = 0; e < 8; e++) {
      int nb = (lcnt[e] + 63) >> 6;
      for (int b = 0; b < nb; b++) { blk_e[tot] = e; blk_r0[tot] = b*64; tot++; }
    }
    *total_nblk = tot;
  }
}

// ---------------- out = x1 + tmp0 + tmp1 ----------------
__global__ __launch_bounds__(256)
void final_add(const float* __restrict__ x1, const bf16* __restrict__ t0,
               const bf16* __restrict__ t1, float* __restrict__ out)
{
  size_t i = ((size_t)blockIdx.x*256 + threadIdx.x) * 4;
  f32x4 a = *(const f32x4*)(x1 + i);
  bf16x4 b0 = *(const bf16x4*)(t0 + i);
  bf16x4 b1 = *(const bf16x4*)(t1 + i);
  f32x4 o;
#pragma unroll
  for (int j = 0; j < 4; j++) o[j] = a[j] + (float)b0[j] + (float)b1[j];
  *(f32x4*)(out + i) = o;
}

// ---------------- flash attention: causal GQA, double-buffered K/V, balanced qt remap ----------------
__global__ __launch_bounds__(256)
void flash(const bf16* __restrict__ qb, const bf16* __restrict__ kb,
           const bf16* __restrict__ vtb, bf16* __restrict__ ob)
{
  __shared__ __align__(16) bf16 Ks[2][64*128];   // [kv][d], XOR-swizzled 16B blocks
  __shared__ __align__(16) bf16 Vs[2][128*64];   // [d][kv], XOR-swizzled
  __shared__ __align__(16) bf16 Ps[4*16*64];     // per-wave P tiles, XOR-swizzled
  const int tid = threadIdx.x, wv = tid >> 6, l = tid & 63;
  const int h = blockIdx.y, g = h >> 2;
  // causal balance: pair qt=x with qt=31-x across the two dispatch halves
  const int qt = (h & 8) ? (31 - (int)blockIdx.x) : (int)blockIdx.x;

  const int qrow = qt*64 + wv*16 + (l & 15);
  bf16x8 qf[4];
#pragma unroll
  for (int f = 0; f < 4; f++)
    qf[f] = *(const bf16x8*)(qb + ((size_t)h*SD + qrow)*DHD + f*32 + (l >> 4)*8);

  float mrun[4], lrun[4];
#pragma unroll
  for (int r = 0; r < 4; r++) { mrun[r] = -1e30f; lrun[r] = 0.f; }
  f32x4 oac[8];
  const f32x4 vz = {0.f, 0.f, 0.f, 0.f};
#pragma unroll
  for (int d = 0; d < 8; d++) oac[d] = vz;

  auto stage = [&](int j, int b) {
#pragma unroll
    for (int c = 0; c < 4; c++) {
      int chunk = wv*4 + c;
      int rk = chunk*4 + (l >> 4);
      int ck = (l & 15) ^ (rk & 7);                       // pre-swizzled global source
      async16(&Ks[b][chunk*512], kb + ((size_t)g*SD + j*64 + rk)*DHD + ck*8);
      int rv = chunk*8 + (l >> 3);
      int cv = (l & 7) ^ (rv & 7);
      async16(&Vs[b][chunk*512], vtb + ((size_t)g*DHD + rv)*SD + j*64 + cv*8);
    }
  };

  stage(0, 0);
  int buf = 0;
  for (int j = 0; j <= qt; ++j) {
    __syncthreads();                      // drains vmcnt -> K/V tile j visible
    if (j < qt) stage(j + 1, buf ^ 1);    // prefetch next tile during compute

    f32x4 sf[4];
#pragma unroll
    for (int n = 0; n < 4; n++) sf[n] = vz;
    __builtin_amdgcn_s_setprio(1);
#pragma unroll
    for (int f = 0; f < 4; f++) {
#pragma unroll
      for (int n = 0; n < 4; n++) {
        int row = n*16 + (l & 15);
        int cb = (f*64 + (l >> 4)*16) ^ ((row & 7) << 4);
        bf16x8 kf = *(const bf16x8*)((const char*)Ks[buf] + row*256 + cb);
        sf[n] = __builtin_amdgcn_mfma_f32_16x16x32_bf16(qf[f], kf, sf[n], 0, 0, 0);
      }
    }
    __builtin_amdgcn_s_setprio(0);
    if (j == qt) {
#pragma unroll
      for (int n = 0; n < 4; n++)
#pragma unroll
        for (int r = 0; r < 4; r++) {
          int kvp = n*16 + (l & 15);
          int qp  = wv*16 + (l >> 4)*4 + r;
          if (kvp > qp) sf[n][r] = -1e30f;
        }
    }
    // online softmax (row spread over 16-lane group; each lane owns 4 q-rows r)
#pragma unroll
    for (int r = 0; r < 4; r++) {
      float tm = fmaxf(fmaxf(sf[0][r], sf[1][r]), fmaxf(sf[2][r], sf[3][r]));
#pragma unroll
      for (int off = 8; off > 0; off >>= 1) tm = fmaxf(tm, __shfl_xor(tm, off));
      float mn = fmaxf(mrun[r], tm);
      float fac = __expf(mrun[r] - mn);
      mrun[r] = mn;
      float pe[4]; float ps = 0.f;
#pragma unroll
      for (int n = 0; n < 4; n++) { pe[n] = __expf(sf[n][r] - mn); ps += pe[n]; }
#pragma unroll
      for (int off = 8; off > 0; off >>= 1) ps += __shfl_xor(ps, off);
      lrun[r] = lrun[r]*fac + ps;
#pragma unroll
      for (int d = 0; d < 8; d++) oac[d][r] *= fac;
      int prow = (l >> 4)*4 + r;
#pragma unroll
      for (int n = 0; n < 4; n++) {
        int cbp = ((n*16 + (l & 15))*2) ^ ((prow & 7) << 4);
        *(bf16*)((char*)Ps + wv*2048 + prow*128 + cbp) = (bf16)pe[n];
      }
    }
    // PV
    __builtin_amdgcn_s_setprio(1);
#pragma unroll
    for (int ks = 0; ks < 2; ks++) {
      int pr = l & 15;
      int cbp = (ks*64 + (l >> 4)*16) ^ ((pr & 7) << 4);
      bf16x8 pa = *(const bf16x8*)((const char*)Ps + wv*2048 + pr*128 + cbp);
#pragma unroll
      for (int dt = 0; dt < 8; dt++) {
        int rv = dt*16 + (l & 15);
        int cbv = (ks*64 + (l >> 4)*16) ^ ((rv & 7) << 4);
        bf16x8 vf = *(const bf16x8*)((const char*)Vs[buf] + rv*128 + cbv);
        oac[dt] = __builtin_amdgcn_mfma_f32_16x16x32_bf16(pa, vf, oac[dt], 0, 0, 0);
      }
    }
    __builtin_amdgcn_s_setprio(0);
    buf ^= 1;
  }
#pragma unroll
  for (int dt = 0; dt < 8; dt++)
#pragma unroll
    for (int r = 0; r < 4; r++) {
      int s = qt*64 + wv*16 + (l >> 4)*4 + r;
      int d = dt*16 + (l & 15);
      ob[(size_t)s*DM + h*DHD + d] = (bf16)(oac[dt][r] / lrun[r]);
    }
}

// ---------------- launch ----------------
extern "C" void kernel_launch(void* const* d_in, const int* in_sizes, int n_in,
                              void* d_out, int out_size, void* d_ws, size_t ws_size,
                              hipStream_t stream) {
  if (ws_size < WS_NEED) return;  // fail loudly (out stays poisoned)
  const float* x     = (const float*)d_in[0];
  const float* ln1_w = (const float*)d_in[1];
  const float* ln2_w = (const float*)d_in[2];
  const float* wq    = (const float*)d_in[3];
  const float* wk    = (const float*)d_in[4];
  const float* wv    = (const float*)d_in[5];
  const float* wo    = (const float*)d_in[6];
  const float* qnw   = (const float*)d_in[7];
  const float* knw   = (const float*)d_in[8];
  const float* rw    = (const float*)d_in[9];
  const float* rb    = (const float*)d_in[10];
  const float* wg    = (const float*)d_in[11];
  const float* wu    = (const float*)d_in[12];
  const float* wd    = (const float*)d_in[13];

  char* ws = (char*)d_ws;
  bf16*  wqkvT = (bf16*)(ws + OF_WQKVT);
  bf16*  wguT  = (bf16*)(ws + OF_WGUT);
  bf16*  wdT   = (bf16*)(ws + OF_WDT);
  bf16*  woT   = (bf16*)(ws + OF_WOT);
  bf16*  hb    = (bf16*)(ws + OF_H);
  float* qkvf  = (float*)(ws + OF_QKV);
  bf16*  qbb   = (bf16*)(ws + OF_QB);
  bf16*  kbb   = (bf16*)(ws + OF_KB);
  bf16*  vtbb  = (bf16*)(ws + OF_VTB);
  float* x1f   = (float*)(ws + OF_X1);
  float* ropet = (float*)(ws + OF_ROPET);
  bf16*  actb  = (bf16*)(ws + OF_ACT);
  bf16*  tbb   = (bf16*)(ws + OF_TB);
  bf16*  obb   = (bf16*)(ws + OF_OB);
  int*   cntp  = (int*)(ws + OF_CNT);
  int*   blke  = (int*)(ws + OF_BLKE);
  int*   blkr  = (int*)(ws + OF_BLKR);
  int*   totp  = (int*)(ws + OF_TOT);
  int*   topi  = (int*)(ws + OF_TOPI);
  float* topw  = (float*)(ws + OF_TOPW);
  int*   idxl  = (int*)(ws + OF_IDXL);
  float* wlst  = (float*)(ws + OF_WLST);
  bf16*  tmp0  = (bf16*)(ws + OF_TMP0);
  bf16*  tmp1  = (bf16*)(ws + OF_TMP1);
  float* outp  = (float*)d_out;

  dim3 b32(32, 8);
  // weight transposes (f32 [K][N] -> bf16 [N][K])
  transpose_cvt<<<dim3(64,64,1), b32, 0, stream>>>(wq, 2048, 0, wqkvT, 2048, 0, 1, 0);
  transpose_cvt<<<dim3(16,64,1), b32, 0, stream>>>(wk,  512, 0, wqkvT, 2048, 0, 1, 2048);
  transpose_cvt<<<dim3(16,64,1), b32, 0, stream>>>(wv,  512, 0, wqkvT, 2048, 0, 1, 2560);
  transpose_cvt<<<dim3(64,64,1), b32, 0, stream>>>(wo, 2048, 0, woT,   2048, 0, 1, 0);
  transpose_cvt<<<dim3(32,64,8), b32, 0, stream>>>(wg, 1024, 2048ll*1024, wguT, 2048, 2048ll*2048, 2, 0);
  transpose_cvt<<<dim3(32,64,8), b32, 0, stream>>>(wu, 1024, 2048ll*1024, wguT, 2048, 2048ll*2048, 2, 1);
  transpose_cvt<<<dim3(64,32,8), b32, 0, stream>>>(wd, 2048, 1024ll*2048, wdT,  1024, 2048ll*1024, 1, 0);
  rope_tab_k<<<256, 256, 0, stream>>>(ropet);

  rmsnorm_k<<<2048, 256, 0, stream>>>(x, ln1_w, hb);
  gemm_bt<0,64><<<dim3(24,32,1), 256, 0, stream>>>(hb, wqkvT, qkvf, nullptr, 2048, 3072, 2048);
  qrope_k<<<2048, 256, 0, stream>>>(qkvf, qnw, ropet, qbb);
  krope_k<<<2048, 128, 0, stream>>>(qkvf, knw, ropet, kbb);
  transpose_cvt<<<dim3(16,64,1), b32, 0, stream>>>(qkvf + 2560, 3072, 0, vtbb, 2048, 0, 1, 0);

  flash<<<dim3(32,16,1), 256, 0, stream>>>(qbb, kbb, vtbb, obb);

  gemm_bt<1,64><<<dim3(16,32,1), 256, 0, stream>>>(obb, woT, x1f, x, 2048, 2048, 2048);
  rmsnorm_k<<<2048, 256, 0, stream>>>(x1f, ln2_w, tbb);
  router_k<<<512, 256, 0, stream>>>(x1f, ln2_w, rw, rb, topi, topw);
  build_k<<<1, 256, 0, stream>>>(topi, topw, cntp, blke, blkr, totp, idxl, wlst);

  // sparse MoE: only routed (token, expert) pairs are computed (64-row blocks)
  gemm_moe_gu<<<dim3(16,72,1), 256, 0, stream>>>(tbb, wguT, actb, cntp, blke, blkr, totp, idxl);
  gemm_moe_dn<<<dim3(16,72,1), 256, 0, stream>>>(actb, wdT, tmp0, tmp1, cntp, blke, blkr, totp, idxl, wlst);
  final_add<<<4096, 256, 0, stream>>>(x1f, tmp0, tmp1, outp);
}

// Round 10
// 593.889 us; speedup vs baseline: 1.5526x; 1.0467x over previous
//
#include <hip/hip_runtime.h>
#include <hip/hip_bf16.h>
#include <stdint.h>
#include <math.h>

typedef __bf16 bf16;
typedef __bf16 bf16x8 __attribute__((ext_vector_type(8)));
typedef __bf16 bf16x4 __attribute__((ext_vector_type(4)));
typedef __bf16 bf16x2 __attribute__((ext_vector_type(2)));
typedef float  f32x4  __attribute__((ext_vector_type(4)));

#define SD 2048      // sequence length
#define DM 2048      // model dim
#define NH 16        // heads
#define NKV 4        // kv heads
#define DHD 128      // head dim
#define NE 8         // experts
#define NNI 1024     // expert intermediate

// ---------------- workspace layout (bytes) ----------------
constexpr size_t OF_WQKVT = 0;                        // bf16 [3072][2048]
constexpr size_t OF_WGUT  = OF_WQKVT + 12582912ull;   // bf16 [8][2048][2048] (gate/up interleaved rows)
constexpr size_t OF_WDT   = OF_WGUT  + 67108864ull;   // bf16 [8][2048][1024]
constexpr size_t OF_WOT   = OF_WDT   + 33554432ull;   // bf16 [2048][2048]   (tb, tmp1 alias later)
constexpr size_t OF_H     = OF_WOT   + 8388608ull;    // bf16 [2048][2048]   (ob, tmp0 alias later)
constexpr size_t OF_QKV   = OF_H     + 8388608ull;    // f32  [2048][3072]
constexpr size_t OF_QB    = OF_QKV   + 25165824ull;   // bf16 [16][2048][128]
constexpr size_t OF_KB    = OF_QB    + 8388608ull;    // bf16 [4][2048][128] (router scratch aliases later)
constexpr size_t OF_VTB   = OF_KB    + 2097152ull;    // bf16 [4][128][2048]
constexpr size_t OF_X1    = OF_VTB   + 2097152ull;    // f32  [2048][2048]  (rope table aliases EARLY)
constexpr size_t WS_NEED  = OF_X1    + 16777216ull;   // 184,549,376 B
// aliases (regions dead by the time these are written):
constexpr size_t OF_ACT  = OF_QKV;          // bf16 [8][2048][1024]
constexpr size_t OF_TB   = OF_WOT;          // bf16 [2048][2048]
constexpr size_t OF_OB   = OF_H;            // bf16 [2048][2048]
constexpr size_t OF_ROPET= OF_X1;           // float [2048][32][2] (x1 written later)
constexpr size_t OF_CNT  = OF_KB;           // int [8]
constexpr size_t OF_BLKE = OF_KB + 512;     // int [128]
constexpr size_t OF_BLKR = OF_KB + 1024;    // int [128]
constexpr size_t OF_TOT  = OF_KB + 1536;    // int [1]
constexpr size_t OF_TOPI = OF_KB + 2048;    // int [2048]
constexpr size_t OF_TOPW = OF_KB + 16384;   // float [2048][2]
constexpr size_t OF_IDXL = OF_KB + 65536;   // int [8][2048]
constexpr size_t OF_WLST = OF_KB + 131072;  // float [8][2048]
constexpr size_t OF_TMP0 = OF_H;            // bf16 [2048][2048]
constexpr size_t OF_TMP1 = OF_WOT;          // bf16 [2048][2048]

// ---------------- async global->LDS (16B/lane, wave-uniform LDS base) ----------------
__device__ __forceinline__ void async16(void* lds, const void* g) {
  uint32_t lo = (uint32_t)(uintptr_t)lds;
  __builtin_amdgcn_global_load_lds(
      (const __attribute__((address_space(1))) uint32_t*)(uintptr_t)g,
      (__attribute__((address_space(3))) uint32_t*)lo,
      16, 0, 0);
}

// ---------------- coalesced 32x32 f32->bf16 transpose tile (bf16x2 stores) ----------------
__device__ __forceinline__ void tr32(const float* __restrict__ ip, int ild,
                                     bf16* __restrict__ op, int old_, int ost, int oroff,
                                     int r0, int c0, int t, float* sm)
{
  int tx = t & 31, ty = t >> 5;
#pragma unroll
  for (int i = 0; i < 4; i++)
    sm[(ty + i*8)*33 + tx] = ip[(size_t)(r0 + ty + i*8)*ild + c0 + tx];
  __syncthreads();
#pragma unroll
  for (int k = 0; k < 2; k++) {
    int p = t + k*256;
    int cl = p >> 4, rp = (p & 15)*2;
    bf16x2 pk = { (bf16)sm[rp*33 + cl], (bf16)sm[(rp+1)*33 + cl] };
    *(bf16x2*)&op[(size_t)((c0 + cl)*ost + oroff)*old_ + r0 + rp] = pk;
  }
}

// ---------------- mega prep: rmsnorm1 + rope table + all 7 weight transposes ----------------
__global__ __launch_bounds__(256)
void prep_k(const float* __restrict__ x, const float* __restrict__ ln1w,
            const float* __restrict__ wq, const float* __restrict__ wk,
            const float* __restrict__ wvv, const float* __restrict__ wo,
            const float* __restrict__ wg, const float* __restrict__ wu,
            const float* __restrict__ wd,
            float* __restrict__ ropet, bf16* __restrict__ hb,
            bf16* __restrict__ wqkvT, bf16* __restrict__ woT,
            bf16* __restrict__ wguT, bf16* __restrict__ wdT)
{
  __shared__ float smem[1056];
  int bid = blockIdx.x, t = threadIdx.x;
  if (bid < 2048) {                       // rmsnorm(x) -> hb
    int s = bid;
    const float* ip = x + (size_t)s * DM;
    float v[8]; float ss = 0.f;
#pragma unroll
    for (int i = 0; i < 8; i++) { v[i] = ip[t + i*256]; ss += v[i]*v[i]; }
#pragma unroll
    for (int off = 32; off > 0; off >>= 1) ss += __shfl_xor(ss, off);
    if ((t & 63) == 0) smem[t >> 6] = ss;
    __syncthreads();
    float rn = rsqrtf((smem[0]+smem[1]+smem[2]+smem[3]) * (1.f/DM) + 1e-6f);
    bf16* op = hb + (size_t)s * DM;
#pragma unroll
    for (int i = 0; i < 8; i++) op[t + i*256] = (bf16)(v[i]*rn*ln1w[t + i*256]);
  } else if (bid < 2304) {                // rope cos/sin table
    int i = (bid - 2048)*256 + t;         // 65536 = 2048*32
    int s = i >> 5, fi = i & 31;
    float ang = (float)s * expf(-(float)fi * (13.815510557964274f/32.f)); // theta=1e6
    float c, sn; sincosf(ang, &sn, &c);
    ropet[i*2]   = c;
    ropet[i*2+1] = sn;
  } else if (bid < 6400) {                // wq
    int j = bid - 2304;
    tr32(wq, 2048, wqkvT, 2048, 1, 0, (j>>6)*32, (j&63)*32, t, smem);
  } else if (bid < 7424) {                // wk
    int j = bid - 6400;
    tr32(wk, 512, wqkvT, 2048, 1, 2048, (j>>4)*32, (j&15)*32, t, smem);
  } else if (bid < 8448) {                // wv
    int j = bid - 7424;
    tr32(wvv, 512, wqkvT, 2048, 1, 2560, (j>>4)*32, (j&15)*32, t, smem);
  } else if (bid < 12544) {               // wo
    int j = bid - 8448;
    tr32(wo, 2048, woT, 2048, 1, 0, (j>>6)*32, (j&63)*32, t, smem);
  } else if (bid < 28928) {               // wg (interleave even rows)
    int j = bid - 12544; int e = j >> 11, r = j & 2047;
    tr32(wg + (size_t)e*2048*1024, 1024, wguT + (size_t)e*2048*2048, 2048, 2, 0,
         (r>>5)*32, (r&31)*32, t, smem);
  } else if (bid < 45312) {               // wu (interleave odd rows)
    int j = bid - 28928; int e = j >> 11, r = j & 2047;
    tr32(wu + (size_t)e*2048*1024, 1024, wguT + (size_t)e*2048*2048, 2048, 2, 1,
         (r>>5)*32, (r&31)*32, t, smem);
  } else {                                // wd
    int j = bid - 45312; int e = j >> 11, r = j & 2047;
    tr32(wd + (size_t)e*1024*2048, 2048, wdT + (size_t)e*2048*1024, 1024, 1, 0,
         (r>>6)*32, (r&63)*32, t, smem);
  }
}

// ---------------- qkv post: qrope + krope + V^T (one kernel) ----------------
__global__ __launch_bounds__(256)
void qkv_post_k(const float* __restrict__ qkvf, const float* __restrict__ qnw,
                const float* __restrict__ knw, const float* __restrict__ ropet,
                bf16* __restrict__ qbb, bf16* __restrict__ kbb, bf16* __restrict__ vtbb)
{
  __shared__ float smem[2052];
  int bid = blockIdx.x, t = threadIdx.x;
  const float2* tab2 = (const float2*)ropet;
  if (bid < 2048) {                       // qrope: rmsnorm(2048) + rope + scale
    int s = bid;
    const float* ip = qkvf + (size_t)s * 3072;
    float* row = smem; float* red = smem + 2048;
    float ss = 0.f;
#pragma unroll
    for (int i = 0; i < 8; i++) { float v = ip[t + i*256]; row[t + i*256] = v; ss += v*v; }
#pragma unroll
    for (int off = 32; off > 0; off >>= 1) ss += __shfl_xor(ss, off);
    if ((t & 63) == 0) red[t >> 6] = ss;
    __syncthreads();
    float rn = rsqrtf((red[0]+red[1]+red[2]+red[3]) * (1.f/2048.f) + 1e-6f);
    const float sc = 0.08838834764831845f; // 1/sqrt(128)
#pragma unroll
    for (int i = 0; i < 8; i++) {
      int idx = t + i*256;
      int d = idx & 127;
      float val = row[idx]*rn*qnw[idx];
      float o;
      if (d < 64) {
        float2 cs = tab2[s*32 + (d & 31)];
        float pv = row[idx ^ 32]*rn*qnw[idx ^ 32];
        o = (d < 32) ? (val*cs.x - pv*cs.y) : (val*cs.x + pv*cs.y);
      } else o = val;
      qbb[((size_t)(idx >> 7)*SD + s)*DHD + d] = (bf16)(o * sc);
    }
  } else if (bid < 4096) {                // krope: rmsnorm(512) + rope
    int s = bid - 2048;
    const float* ip = qkvf + (size_t)s * 3072 + 2048;
    float* row = smem; float* red = smem + 512;
    float v0 = ip[t], v1 = ip[t + 256];
    row[t] = v0; row[t + 256] = v1;
    float ss = v0*v0 + v1*v1;
#pragma unroll
    for (int off = 32; off > 0; off >>= 1) ss += __shfl_xor(ss, off);
    if ((t & 63) == 0) red[t >> 6] = ss;
    __syncthreads();
    float rn = rsqrtf((red[0]+red[1]+red[2]+red[3]) * (1.f/512.f) + 1e-6f);
#pragma unroll
    for (int i = 0; i < 2; i++) {
      int idx = t + i*256;
      int d = idx & 127;
      float val = row[idx]*rn*knw[idx];
      float o;
      if (d < 64) {
        float2 cs = tab2[s*32 + (d & 31)];
        float pv = row[idx ^ 32]*rn*knw[idx ^ 32];
        o = (d < 32) ? (val*cs.x - pv*cs.y) : (val*cs.x + pv*cs.y);
      } else o = val;
      kbb[((size_t)(idx >> 7)*SD + s)*DHD + d] = (bf16)o;
    }
  } else {                                // V^T: [s][512] f32 -> [512][2048] bf16
    int j = bid - 4096;
    tr32(qkvf + 2560, 3072, vtbb, 2048, 1, 0, (j>>4)*32, (j&15)*32, t, smem);
  }
}

// ---------------- GEMM 128x128: C[M][N] = A @ BT^T, flat grid + XCD swizzle ----------------
// EPI 0: C f32 plain    1: C = acc + res
template<int EPI>
__global__ __launch_bounds__(256)
void gemm_bt(const bf16* __restrict__ A, const bf16* __restrict__ BT,
             float* __restrict__ Cg, const float* __restrict__ res,
             int N, int K, int nbm)
{
  __shared__ __align__(16) bf16 As[2][128*32];
  __shared__ __align__(16) bf16 Bs[2][128*32];
  const int nwg = gridDim.x, cpx = nwg >> 3;
  const int id = blockIdx.x;
  const int swz = (id & 7)*cpx + (id >> 3);         // XCD-chunked, bijective (nwg%8==0)
  const int bm = (swz % nbm)*128, bn = (swz / nbm)*128;   // bn-major: few B-panels per XCD
  const int tid = threadIdx.x;
  const int wv = tid >> 6, l = tid & 63;
  const int wm = wv >> 1, wn = wv & 1;

  f32x4 acc[4][4];
  const f32x4 vz = {0.f, 0.f, 0.f, 0.f};
#pragma unroll
  for (int i = 0; i < 4; i++)
#pragma unroll
    for (int j = 0; j < 4; j++) acc[i][j] = vz;

  auto stage = [&](int kt, int b) {
    int k0 = kt * 32;
    int kc = (l & 3) * 8;
#pragma unroll
    for (int c = 0; c < 2; c++) {
      int chunk = wv*2 + c;
      int row = chunk*16 + (l >> 2);
      async16(&As[b][chunk*512], A  + (size_t)(bm + row)*K + k0 + kc);
      async16(&Bs[b][chunk*512], BT + (size_t)(bn + row)*K + k0 + kc);
    }
  };

  int nkt = K >> 5;
  stage(0, 0);
  int buf = 0;
  for (int kt = 0; kt < nkt; ++kt) {
    __syncthreads();                    // drains vmcnt -> staged tile visible
    if (kt + 1 < nkt) stage(kt + 1, buf ^ 1);
    bf16x8 af[4], bfv[4];
#pragma unroll
    for (int m = 0; m < 4; m++)
      af[m] = *(const bf16x8*)&As[buf][(wm*64 + m*16 + (l & 15))*32 + (l >> 4)*8];
#pragma unroll
    for (int n = 0; n < 4; n++)
      bfv[n] = *(const bf16x8*)&Bs[buf][(wn*64 + n*16 + (l & 15))*32 + (l >> 4)*8];
#pragma unroll
    for (int m = 0; m < 4; m++)
#pragma unroll
      for (int n = 0; n < 4; n++)
        acc[m][n] = __builtin_amdgcn_mfma_f32_16x16x32_bf16(af[m], bfv[n], acc[m][n], 0, 0, 0);
    buf ^= 1;
  }

#pragma unroll
  for (int m = 0; m < 4; m++) {
#pragma unroll
    for (int n = 0; n < 4; n++) {
#pragma unroll
      for (int r = 0; r < 4; r++) {
        int row = bm + wm*64 + m*16 + (l >> 4)*4 + r;
        int col = bn + wn*64 + n*16 + (l & 15);
        float v = acc[m][n][r];
        if (EPI == 0) Cg[(size_t)row*N + col] = v;
        else          Cg[(size_t)row*N + col] = v + res[(size_t)row*N + col];
      }
    }
  }
}

// ---------------- MoE gate/up GEMM: 128-row gathered blocks, silu(gate)*up ----------------
__global__ __launch_bounds__(256)
void gemm_moe_gu(const bf16* __restrict__ tb, const bf16* __restrict__ wgu,
                 bf16* __restrict__ act,
                 const int* __restrict__ cnt, const int* __restrict__ blk_e,
                 const int* __restrict__ blk_r0, const int* __restrict__ total_nblk,
                 const int* __restrict__ idxlist)
{
  const int nwg = gridDim.x, cpx = nwg >> 3;
  const int id = blockIdx.x;
  const int swz = (id & 7)*cpx + (id >> 3);
  const int bn = (swz / 40)*128;
  const int by = swz % 40;
  if (by >= *total_nblk) return;
  const int e = blk_e[by], r0 = blk_r0[by], cn = cnt[e];
  __shared__ __align__(16) bf16 As[2][128*32];
  __shared__ __align__(16) bf16 Bs[2][128*32];
  const int tid = threadIdx.x;
  const int wv = tid >> 6, l = tid & 63;
  const int wm = wv >> 1, wn = wv & 1;
  const bf16* BT = wgu + (size_t)e*2048*2048;

  // gathered A row pointers (K-loop invariant)
  const bf16* Arow[2];
#pragma unroll
  for (int c = 0; c < 2; c++) {
    int chunk = wv*2 + c;
    int rp = r0 + chunk*16 + (l >> 2);
    int tok = (rp < cn) ? (idxlist[e*2048 + rp] & 0xFFFF) : 0;
    Arow[c] = tb + (size_t)tok*2048 + (l & 3)*8;
  }

  f32x4 acc[4][4];
  const f32x4 vz = {0.f, 0.f, 0.f, 0.f};
#pragma unroll
  for (int i = 0; i < 4; i++)
#pragma unroll
    for (int j = 0; j < 4; j++) acc[i][j] = vz;

  auto stage = [&](int kt, int b) {
    int k0 = kt * 32;
    int kc = (l & 3) * 8;
#pragma unroll
    for (int c = 0; c < 2; c++) {
      int chunk = wv*2 + c;
      int row = chunk*16 + (l >> 2);
      async16(&As[b][chunk*512], Arow[c] + k0);
      async16(&Bs[b][chunk*512], BT + (size_t)(bn + row)*2048 + k0 + kc);
    }
  };

  stage(0, 0);
  int buf = 0;
  for (int kt = 0; kt < 64; ++kt) {
    __syncthreads();
    if (kt + 1 < 64) stage(kt + 1, buf ^ 1);
    bf16x8 af[4], bfv[4];
#pragma unroll
    for (int m = 0; m < 4; m++)
      af[m] = *(const bf16x8*)&As[buf][(wm*64 + m*16 + (l & 15))*32 + (l >> 4)*8];
#pragma unroll
    for (int n = 0; n < 4; n++)
      bfv[n] = *(const bf16x8*)&Bs[buf][(wn*64 + n*16 + (l & 15))*32 + (l >> 4)*8];
#pragma unroll
    for (int m = 0; m < 4; m++)
#pragma unroll
      for (int n = 0; n < 4; n++)
        acc[m][n] = __builtin_amdgcn_mfma_f32_16x16x32_bf16(af[m], bfv[n], acc[m][n], 0, 0, 0);
    buf ^= 1;
  }

  bf16* ap = act + (size_t)e*2048*1024;
#pragma unroll
  for (int m = 0; m < 4; m++) {
#pragma unroll
    for (int n = 0; n < 4; n++) {
#pragma unroll
      for (int r = 0; r < 4; r++) {
        int lrow = wm*64 + m*16 + (l >> 4)*4 + r;
        int col = bn + wn*64 + n*16 + (l & 15);
        float v = acc[m][n][r];
        float p = __shfl_xor(v, 1);        // partner column (gate<->up pair)
        if (!(l & 1)) {
          float a = v / (1.f + __expf(-v)) * p;   // silu(gate)*up
          ap[(size_t)(r0 + lrow)*1024 + (col >> 1)] = (bf16)a;
        }
      }
    }
  }
}

// ---------------- MoE down GEMM: 128-row blocks, scatter w*acc to rank buffers ----------------
__global__ __launch_bounds__(256)
void gemm_moe_dn(const bf16* __restrict__ act, const bf16* __restrict__ wdt,
                 bf16* __restrict__ tmp0, bf16* __restrict__ tmp1,
                 const int* __restrict__ cnt, const int* __restrict__ blk_e,
                 const int* __restrict__ blk_r0, const int* __restrict__ total_nblk,
                 const int* __restrict__ idxlist, const float* __restrict__ wlist)
{
  const int nwg = gridDim.x, cpx = nwg >> 3;
  const int id = blockIdx.x;
  const int swz = (id & 7)*cpx + (id >> 3);
  const int bn = (swz / 40)*128;
  const int by = swz % 40;
  if (by >= *total_nblk) return;
  const int e = blk_e[by], r0 = blk_r0[by], cn = cnt[e];
  __shared__ __align__(16) bf16 As[2][128*32];
  __shared__ __align__(16) bf16 Bs[2][128*32];
  const int tid = threadIdx.x;
  const int wv = tid >> 6, l = tid & 63;
  const int wm = wv >> 1, wn = wv & 1;
  const bf16* A  = act + (size_t)e*2048*1024 + (size_t)r0*1024;
  const bf16* BT = wdt + (size_t)e*2048*1024;

  f32x4 acc[4][4];
  const f32x4 vz = {0.f, 0.f, 0.f, 0.f};
#pragma unroll
  for (int i = 0; i < 4; i++)
#pragma unroll
    for (int j = 0; j < 4; j++) acc[i][j] = vz;

  auto stage = [&](int kt, int b) {
    int k0 = kt * 32;
    int kc = (l & 3) * 8;
#pragma unroll
    for (int c = 0; c < 2; c++) {
      int chunk = wv*2 + c;
      int row = chunk*16 + (l >> 2);
      async16(&As[b][chunk*512], A  + (size_t)row*1024 + k0 + kc);
      async16(&Bs[b][chunk*512], BT + (size_t)(bn + row)*1024 + k0 + kc);
    }
  };

  stage(0, 0);
  int buf = 0;
  for (int kt = 0; kt < 32; ++kt) {
    __syncthreads();
    if (kt + 1 < 32) stage(kt + 1, buf ^ 1);
    bf16x8 af[4], bfv[4];
#pragma unroll
    for (int m = 0; m < 4; m++)
      af[m] = *(const bf16x8*)&As[buf][(wm*64 + m*16 + (l & 15))*32 + (l >> 4)*8];
#pragma unroll
    for (int n = 0; n < 4; n++)
      bfv[n] = *(const bf16x8*)&Bs[buf][(wn*64 + n*16 + (l & 15))*32 + (l >> 4)*8];
#pragma unroll
    for (int m = 0; m < 4; m++)
#pragma unroll
      for (int n = 0; n < 4; n++)
        acc[m][n] = __builtin_amdgcn_mfma_f32_16x16x32_bf16(af[m], bfv[n], acc[m][n], 0, 0, 0);
    buf ^= 1;
  }

#pragma unroll
  for (int m = 0; m < 4; m++) {
#pragma unroll
    for (int n = 0; n < 4; n++) {
#pragma unroll
      for (int r = 0; r < 4; r++) {
        int lrow = wm*64 + m*16 + (l >> 4)*4 + r;
        int rie = r0 + lrow;
        if (rie < cn) {
          int col = bn + wn*64 + n*16 + (l & 15);
          int pk = idxlist[e*2048 + rie];
          int tkn = pk & 0xFFFF, rank = pk >> 16;
          float w = wlist[e*2048 + rie];
          bf16* dst = rank ? tmp1 : tmp0;
          dst[(size_t)tkn*2048 + col] = (bf16)(w * acc[m][n][r]);
        }
      }
    }
  }
}

// ---------------- rmsnorm f32 [S][2048] -> bf16 ----------------
__global__ __launch_bounds__(256)
void rmsnorm_k(const float* __restrict__ in, const float* __restrict__ w, bf16* __restrict__ outb)
{
  __shared__ float red[4];
  int s = blockIdx.x, t = threadIdx.x;
  const float* ip = in + (size_t)s * DM;
  float v[8]; float ss = 0.f;
#pragma unroll
  for (int i = 0; i < 8; i++) { v[i] = ip[t + i*256]; ss += v[i]*v[i]; }
#pragma unroll
  for (int off = 32; off > 0; off >>= 1) ss += __shfl_xor(ss, off);
  if ((t & 63) == 0) red[t >> 6] = ss;
  __syncthreads();
  float rn = rsqrtf((red[0]+red[1]+red[2]+red[3]) * (1.f/DM) + 1e-6f);
  bf16* op = outb + (size_t)s * DM;
#pragma unroll
  for (int i = 0; i < 8; i++) op[t + i*256] = (bf16)(v[i]*rn*w[t + i*256]);
}

// ---------------- router: f32 path from x1 (own rmsnorm), sigmoid top-2 per token ----------------
__global__ __launch_bounds__(256)
void router_k(const float* __restrict__ x1, const float* __restrict__ w2,
              const float* __restrict__ rw, const float* __restrict__ rb,
              int* __restrict__ top_i, float* __restrict__ top_w)
{
  int tok = blockIdx.x*4 + (threadIdx.x >> 6);
  int l = threadIdx.x & 63;
  const float* ip = x1 + (size_t)tok * DM;
  float tv[32]; float ss = 0.f;
#pragma unroll
  for (int i = 0; i < 32; i++) { float v = ip[l + i*64]; tv[i] = v; ss += v*v; }
#pragma unroll
  for (int off = 32; off > 0; off >>= 1) ss += __shfl_xor(ss, off);
  float rn = rsqrtf(ss * (1.f/DM) + 1e-6f);
  float acc[8];
#pragma unroll
  for (int e = 0; e < 8; e++) acc[e] = 0.f;
#pragma unroll
  for (int i = 0; i < 32; i++) {
    int d = l + i*64;
    float tval = tv[i]*rn*w2[d];
#pragma unroll
    for (int e = 0; e < 8; e++) acc[e] += tval * rw[d*8 + e];
  }
#pragma unroll
  for (int e = 0; e < 8; e++)
#pragma unroll
    for (int off = 32; off > 0; off >>= 1) acc[e] += __shfl_xor(acc[e], off);
  if (l == 0) {
    float sig[8], scv[8];
#pragma unroll
    for (int e = 0; e < 8; e++) { sig[e] = 1.f/(1.f + expf(-acc[e])); scv[e] = sig[e] + rb[e]; }
    int i0 = 0;
#pragma unroll
    for (int e = 1; e < 8; e++) if (scv[e] > scv[i0]) i0 = e;
    int i1 = (i0 == 0) ? 1 : 0;
#pragma unroll
    for (int e = 0; e < 8; e++) if (e != i0 && scv[e] > scv[i1]) i1 = e;
    float a0 = sig[i0], a1 = sig[i1], inv = 1.f/(a0 + a1);
    top_i[tok] = i0 | (i1 << 8);
    top_w[tok*2]   = a0*inv;
    top_w[tok*2+1] = a1*inv;
  }
}

// ---------------- build per-expert lists + 128-row block schedule (1 block) ----------------
__global__ __launch_bounds__(256)
void build_k(const int* __restrict__ top_i, const float* __restrict__ top_w,
             int* __restrict__ cnt, int* __restrict__ blk_e, int* __restrict__ blk_r0,
             int* __restrict__ total_nblk, int* __restrict__ idxlist, float* __restrict__ wlist)
{
  __shared__ int lcnt[8];
  int tid = threadIdx.x;
  if (tid < 8) lcnt[tid] = 0;
  __syncthreads();
  for (int t = tid; t < SD; t += 256) {
    int pk = top_i[t];
    int i0 = pk & 0xFF, i1 = (pk >> 8) & 0xFF;
    int p0 = atomicAdd(&lcnt[i0], 1);
    idxlist[i0*2048 + p0] = t;             // rank 0
    wlist [i0*2048 + p0] = top_w[t*2];
    int p1 = atomicAdd(&lcnt[i1], 1);
    idxlist[i1*2048 + p1] = t | (1 << 16); // rank 1
    wlist [i1*2048 + p1] = top_w[t*2+1];
  }
  __syncthreads();
  if (tid < 8) cnt[tid] = lcnt[tid];
  if (tid == 0) {
    int tot = 0;
    for (int e = 0; e < 8; e++) {
      int nb = (lcnt[e] + 127) >> 7;
      for (int b = 0; b < nb; b++) { blk_e[tot] = e; blk_r0[tot] = b*128; tot++; }
    }
    *total_nblk = tot;
  }
}

// ---------------- out = x1 + tmp0 + tmp1 ----------------
__global__ __launch_bounds__(256)
void final_add(const float* __restrict__ x1, const bf16* __restrict__ t0,
               const bf16* __restrict__ t1, float* __restrict__ out)
{
  size_t i = ((size_t)blockIdx.x*256 + threadIdx.x) * 4;
  f32x4 a = *(const f32x4*)(x1 + i);
  bf16x4 b0 = *(const bf16x4*)(t0 + i);
  bf16x4 b1 = *(const bf16x4*)(t1 + i);
  f32x4 o;
#pragma unroll
  for (int j = 0; j < 4; j++) o[j] = a[j] + (float)b0[j] + (float)b1[j];
  *(f32x4*)(out + i) = o;
}

// ---------------- flash attention: causal GQA, double-buffered K/V, balanced qt remap ----------------
__global__ __launch_bounds__(256)
void flash(const bf16* __restrict__ qb, const bf16* __restrict__ kb,
           const bf16* __restrict__ vtb, bf16* __restrict__ ob)
{
  __shared__ __align__(16) bf16 Ks[2][64*128];   // [kv][d], XOR-swizzled 16B blocks
  __shared__ __align__(16) bf16 Vs[2][128*64];   // [d][kv], XOR-swizzled
  __shared__ __align__(16) bf16 Ps[4*16*64];     // per-wave P tiles, XOR-swizzled
  const int tid = threadIdx.x, wv = tid >> 6, l = tid & 63;
  const int h = blockIdx.y, g = h >> 2;
  const int qt = (h & 8) ? (31 - (int)blockIdx.x) : (int)blockIdx.x;

  const int qrow = qt*64 + wv*16 + (l & 15);
  bf16x8 qf[4];
#pragma unroll
  for (int f = 0; f < 4; f++)
    qf[f] = *(const bf16x8*)(qb + ((size_t)h*SD + qrow)*DHD + f*32 + (l >> 4)*8);

  float mrun[4], lrun[4];
#pragma unroll
  for (int r = 0; r < 4; r++) { mrun[r] = -1e30f; lrun[r] = 0.f; }
  f32x4 oac[8];
  const f32x4 vz = {0.f, 0.f, 0.f, 0.f};
#pragma unroll
  for (int d = 0; d < 8; d++) oac[d] = vz;

  auto stage = [&](int j, int b) {
#pragma unroll
    for (int c = 0; c < 4; c++) {
      int chunk = wv*4 + c;
      int rk = chunk*4 + (l >> 4);
      int ck = (l & 15) ^ (rk & 7);
      async16(&Ks[b][chunk*512], kb + ((size_t)g*SD + j*64 + rk)*DHD + ck*8);
      int rv = chunk*8 + (l >> 3);
      int cv = (l & 7) ^ (rv & 7);
      async16(&Vs[b][chunk*512], vtb + ((size_t)g*DHD + rv)*SD + j*64 + cv*8);
    }
  };

  stage(0, 0);
  int buf = 0;
  for (int j = 0; j <= qt; ++j) {
    __syncthreads();
    if (j < qt) stage(j + 1, buf ^ 1);

    f32x4 sf[4];
#pragma unroll
    for (int n = 0; n < 4; n++) sf[n] = vz;
    __builtin_amdgcn_s_setprio(1);
#pragma unroll
    for (int f = 0; f < 4; f++) {
#pragma unroll
      for (int n = 0; n < 4; n++) {
        int row = n*16 + (l & 15);
        int cb = (f*64 + (l >> 4)*16) ^ ((row & 7) << 4);
        bf16x8 kf = *(const bf16x8*)((const char*)Ks[buf] + row*256 + cb);
        sf[n] = __builtin_amdgcn_mfma_f32_16x16x32_bf16(qf[f], kf, sf[n], 0, 0, 0);
      }
    }
    __builtin_amdgcn_s_setprio(0);
    if (j == qt) {
#pragma unroll
      for (int n = 0; n < 4; n++)
#pragma unroll
        for (int r = 0; r < 4; r++) {
          int kvp = n*16 + (l & 15);
          int qp  = wv*16 + (l >> 4)*4 + r;
          if (kvp > qp) sf[n][r] = -1e30f;
        }
    }
#pragma unroll
    for (int r = 0; r < 4; r++) {
      float tm = fmaxf(fmaxf(sf[0][r], sf[1][r]), fmaxf(sf[2][r], sf[3][r]));
#pragma unroll
      for (int off = 8; off > 0; off >>= 1) tm = fmaxf(tm, __shfl_xor(tm, off));
      float mn = fmaxf(mrun[r], tm);
      float fac = __expf(mrun[r] - mn);
      mrun[r] = mn;
      float pe[4]; float ps = 0.f;
#pragma unroll
      for (int n = 0; n < 4; n++) { pe[n] = __expf(sf[n][r] - mn); ps += pe[n]; }
#pragma unroll
      for (int off = 8; off > 0; off >>= 1) ps += __shfl_xor(ps, off);
      lrun[r] = lrun[r]*fac + ps;
#pragma unroll
      for (int d = 0; d < 8; d++) oac[d][r] *= fac;
      int prow = (l >> 4)*4 + r;
#pragma unroll
      for (int n = 0; n < 4; n++) {
        int cbp = ((n*16 + (l & 15))*2) ^ ((prow & 7) << 4);
        *(bf16*)((char*)Ps + wv*2048 + prow*128 + cbp) = (bf16)pe[n];
      }
    }
    __builtin_amdgcn_s_setprio(1);
#pragma unroll
    for (int ks = 0; ks < 2; ks++) {
      int pr = l & 15;
      int cbp = (ks*64 + (l >> 4)*16) ^ ((pr & 7) << 4);
      bf16x8 pa = *(const bf16x8*)((const char*)Ps + wv*2048 + pr*128 + cbp);
#pragma unroll
      for (int dt = 0; dt < 8; dt++) {
        int rv = dt*16 + (l & 15);
        int cbv = (ks*64 + (l >> 4)*16) ^ ((rv & 7) << 4);
        bf16x8 vf = *(const bf16x8*)((const char*)Vs[buf] + rv*128 + cbv);
        oac[dt] = __builtin_amdgcn_mfma_f32_16x16x32_bf16(pa, vf, oac[dt], 0, 0, 0);
      }
    }
    __builtin_amdgcn_s_setprio(0);
    buf ^= 1;
  }
#pragma unroll
  for (int dt = 0; dt < 8; dt++)
#pragma unroll
    for (int r = 0; r < 4; r++) {
      int s = qt*64 + wv*16 + (l >> 4)*4 + r;
      int d = dt*16 + (l & 15);
      ob[(size_t)s*DM + h*DHD + d] = (bf16)(oac[dt][r] / lrun[r]);
    }
}

// ---------------- launch ----------------
extern "C" void kernel_launch(void* const* d_in, const int* in_sizes, int n_in,
                              void* d_out, int out_size, void* d_ws, size_t ws_size,
                              hipStream_t stream) {
  if (ws_size < WS_NEED) return;  // fail loudly (out stays poisoned)
  const float* x     = (const float*)d_in[0];
  const float* ln1_w = (const float*)d_in[1];
  const float* ln2_w = (const float*)d_in[2];
  const float* wq    = (const float*)d_in[3];
  const float* wk    = (const float*)d_in[4];
  const float* wv    = (const float*)d_in[5];
  const float* wo    = (const float*)d_in[6];
  const float* qnw   = (const float*)d_in[7];
  const float* knw   = (const float*)d_in[8];
  const float* rw    = (const float*)d_in[9];
  const float* rb    = (const float*)d_in[10];
  const float* wg    = (const float*)d_in[11];
  const float* wu    = (const float*)d_in[12];
  const float* wd    = (const float*)d_in[13];

  char* ws = (char*)d_ws;
  bf16*  wqkvT = (bf16*)(ws + OF_WQKVT);
  bf16*  wguT  = (bf16*)(ws + OF_WGUT);
  bf16*  wdT   = (bf16*)(ws + OF_WDT);
  bf16*  woT   = (bf16*)(ws + OF_WOT);
  bf16*  hb    = (bf16*)(ws + OF_H);
  float* qkvf  = (float*)(ws + OF_QKV);
  bf16*  qbb   = (bf16*)(ws + OF_QB);
  bf16*  kbb   = (bf16*)(ws + OF_KB);
  bf16*  vtbb  = (bf16*)(ws + OF_VTB);
  float* x1f   = (float*)(ws + OF_X1);
  float* ropet = (float*)(ws + OF_ROPET);
  bf16*  actb  = (bf16*)(ws + OF_ACT);
  bf16*  tbb   = (bf16*)(ws + OF_TB);
  bf16*  obb   = (bf16*)(ws + OF_OB);
  int*   cntp  = (int*)(ws + OF_CNT);
  int*   blke  = (int*)(ws + OF_BLKE);
  int*   blkr  = (int*)(ws + OF_BLKR);
  int*   totp  = (int*)(ws + OF_TOT);
  int*   topi  = (int*)(ws + OF_TOPI);
  float* topw  = (float*)(ws + OF_TOPW);
  int*   idxl  = (int*)(ws + OF_IDXL);
  float* wlst  = (float*)(ws + OF_WLST);
  bf16*  tmp0  = (bf16*)(ws + OF_TMP0);
  bf16*  tmp1  = (bf16*)(ws + OF_TMP1);
  float* outp  = (float*)d_out;

  // 1. mega-prep: rmsnorm1 + rope table + all weight transposes
  prep_k<<<61696, 256, 0, stream>>>(x, ln1_w, wq, wk, wv, wo, wg, wu, wd,
                                    ropet, hb, wqkvT, woT, wguT, wdT);
  // 2. qkv projection
  gemm_bt<0><<<384, 256, 0, stream>>>(hb, wqkvT, qkvf, nullptr, 3072, 2048, 16);
  // 3. q/k norm+rope + V^T
  qkv_post_k<<<5120, 256, 0, stream>>>(qkvf, qnw, knw, ropet, qbb, kbb, vtbb);
  // 4. attention
  flash<<<dim3(32,16,1), 256, 0, stream>>>(qbb, kbb, vtbb, obb);
  // 5. o-proj + residual
  gemm_bt<1><<<256, 256, 0, stream>>>(obb, woT, x1f, x, 2048, 2048, 16);
  // 6-8. rmsnorm2, router, schedule build
  rmsnorm_k<<<2048, 256, 0, stream>>>(x1f, ln2_w, tbb);
  router_k<<<512, 256, 0, stream>>>(x1f, ln2_w, rw, rb, topi, topw);
  build_k<<<1, 256, 0, stream>>>(topi, topw, cntp, blke, blkr, totp, idxl, wlst);
  // 9-10. sparse MoE
  gemm_moe_gu<<<640, 256, 0, stream>>>(tbb, wguT, actb, cntp, blke, blkr, totp, idxl);
  gemm_moe_dn<<<640, 256, 0, stream>>>(actb, wdT, tmp0, tmp1, cntp, blke, blkr, totp, idxl, wlst);
  // 11. final residual add
  final_add<<<4096, 256, 0, stream>>>(x1f, tmp0, tmp1, outp);
}